// Round 3
// baseline (1744.023 us; speedup 1.0000x reference)
//
#include <hip/hip_runtime.h>
#include <cmath>

#define TM 128
#define TN 128
#define TK 16
#define LDSW 132          // padded LDS row width (floats)

// Protection bands for discrete decision boundaries.  Fast-path errors are
// ~1e-6 (fp32 GEMM acc + fp32 sigmoid); bands give >=20x margin.  Flagged
// rows are recomputed fully in fp64 by row_exact (cost bounded ~30us even
// if 100% of rows flag, since blocks run 2048-wide).
#define B03  1e-4f        // g vs 0.3 (comp zeroing)
#define B01  1e-4f        // |comp| vs 0.1 (sparsity count)
#define BDYN 2e-5f        // |dyn| vs thr (final mask)

// ---------------------------------------------------------------------------
// Shared 128x128x16 fp32 tile mainloop (validated round 2).  Double-buffered
// LDS ping-pong, one barrier per K-step, bitwise-stable acc order.
// ---------------------------------------------------------------------------
#define STAGE_STORE(B)                                                          \
        As[B][aq * 4 + 0][ar] = pa0.x; As[B][aq * 4 + 1][ar] = pa0.y;           \
        As[B][aq * 4 + 2][ar] = pa0.z; As[B][aq * 4 + 3][ar] = pa0.w;           \
        As[B][aq * 4 + 0][ar + 64] = pa1.x; As[B][aq * 4 + 1][ar + 64] = pa1.y; \
        As[B][aq * 4 + 2][ar + 64] = pa1.z; As[B][aq * 4 + 3][ar + 64] = pa1.w; \
        *(float4*)&Bs[B][bk][bn4] = pb0;                                        \
        *(float4*)&Bs[B][bk + 8][bn4] = pb1;

#define GEMM_MAINLOOP(Aptr, Wptr, Kdim, Ndim)                                   \
    __shared__ float As[2][TK][LDSW];                                           \
    __shared__ float Bs[2][TK][LDSW];                                           \
    const int tid = threadIdx.x;                                                \
    const int bm = blockIdx.x * TM;                                             \
    const int bn = blockIdx.y * TN;                                             \
    const int tx = tid & 15, ty = tid >> 4;                                     \
    const int ar = tid >> 2, aq = tid & 3;                                      \
    const int bk = tid >> 5, bn4 = (tid & 31) * 4;                              \
    float acc[2][2][4][4];                                                      \
    _Pragma("unroll") for (int a = 0; a < 2; ++a)                               \
    _Pragma("unroll") for (int b = 0; b < 2; ++b)                               \
    _Pragma("unroll") for (int i = 0; i < 4; ++i)                               \
    _Pragma("unroll") for (int j = 0; j < 4; ++j) acc[a][b][i][j] = 0.f;        \
    float4 pa0 = *(const float4*)((Aptr) + (size_t)(bm + ar) * (Kdim) + aq * 4);      \
    float4 pa1 = *(const float4*)((Aptr) + (size_t)(bm + ar + 64) * (Kdim) + aq * 4); \
    float4 pb0 = *(const float4*)((Wptr) + (size_t)bk * (Ndim) + bn + bn4);           \
    float4 pb1 = *(const float4*)((Wptr) + (size_t)(bk + 8) * (Ndim) + bn + bn4);     \
    STAGE_STORE(0)                                                              \
    __syncthreads();                                                            \
    int buf = 0;                                                                \
    for (int k0 = 0; k0 < (Kdim); k0 += TK) {                                   \
        const int nk = k0 + TK;                                                 \
        if (nk < (Kdim)) {                                                      \
            pa0 = *(const float4*)((Aptr) + (size_t)(bm + ar) * (Kdim) + nk + aq * 4);      \
            pa1 = *(const float4*)((Aptr) + (size_t)(bm + ar + 64) * (Kdim) + nk + aq * 4); \
            pb0 = *(const float4*)((Wptr) + (size_t)(nk + bk) * (Ndim) + bn + bn4);         \
            pb1 = *(const float4*)((Wptr) + (size_t)(nk + bk + 8) * (Ndim) + bn + bn4);     \
        }                                                                       \
        _Pragma("unroll") for (int k = 0; k < TK; ++k) {                        \
            float4 da0 = *(const float4*)&As[buf][k][ty * 4];                   \
            float4 da1 = *(const float4*)&As[buf][k][64 + ty * 4];              \
            float4 db0 = *(const float4*)&Bs[buf][k][tx * 4];                   \
            float4 db1 = *(const float4*)&Bs[buf][k][64 + tx * 4];              \
            const float* dap[2] = {&da0.x, &da1.x};                             \
            const float* dbp[2] = {&db0.x, &db1.x};                             \
            _Pragma("unroll") for (int a = 0; a < 2; ++a)                       \
            _Pragma("unroll") for (int b = 0; b < 2; ++b)                       \
            _Pragma("unroll") for (int i = 0; i < 4; ++i)                       \
            _Pragma("unroll") for (int j = 0; j < 4; ++j)                       \
                acc[a][b][i][j] = fmaf(dap[a][i], dbp[b][j], acc[a][b][i][j]);  \
        }                                                                       \
        if (nk < (Kdim)) {                                                      \
            const int nb = buf ^ 1;                                             \
            STAGE_STORE(nb)                                                     \
            __syncthreads();                                                    \
            buf = nb;                                                           \
        }                                                                       \
    }

// ---------------------------------------------------------------------------
// K1: h1 = relu(F @ Wg1 + b1), fp32.  F:[M,1024], Wg1:[1024,256], out:[M,256]
// ---------------------------------------------------------------------------
__global__ __launch_bounds__(256) void gemm1_f32(
    const float* __restrict__ A, const float* __restrict__ W,
    const float* __restrict__ bias, float* __restrict__ out, int M)
{
    const int K = 1024, N = 256;
    GEMM_MAINLOOP(A, W, K, N)
    #pragma unroll
    for (int a = 0; a < 2; ++a) {
        #pragma unroll
        for (int b = 0; b < 2; ++b) {
            const int col = bn + b * 64 + tx * 4;
            float4 bi = *(const float4*)(bias + col);
            #pragma unroll
            for (int i = 0; i < 4; ++i) {
                const int row = bm + a * 64 + ty * 4 + i;
                float4 o;
                o.x = fmaxf(acc[a][b][i][0] + bi.x, 0.f);
                o.y = fmaxf(acc[a][b][i][1] + bi.y, 0.f);
                o.z = fmaxf(acc[a][b][i][2] + bi.z, 0.f);
                o.w = fmaxf(acc[a][b][i][3] + bi.w, 0.f);
                *(float4*)(out + (size_t)row * N + col) = o;
            }
        }
    }
}

// ---------------------------------------------------------------------------
// K2: z2 = h1 @ Wg2 + b2; g = F * sigmoid(z2); comp = (g>0.3)?0:g.
// Epilogue fp32 (fast): decision boundaries are protected by row flags +
// row_exact fp64 recompute, so fp32 sigmoid error (~2e-7) is safe.
// ---------------------------------------------------------------------------
__global__ __launch_bounds__(256) void gemm2_f32(
    const float* __restrict__ A, const float* __restrict__ W,
    const float* __restrict__ bias, const float* __restrict__ F,
    float* __restrict__ out, unsigned* __restrict__ flags, int M)
{
    const int K = 256, N = 1024;
    GEMM_MAINLOOP(A, W, K, N)
    #pragma unroll
    for (int a = 0; a < 2; ++a) {
        #pragma unroll
        for (int b = 0; b < 2; ++b) {
            const int col = bn + b * 64 + tx * 4;
            float4 bi = *(const float4*)(bias + col);
            const float* bip = &bi.x;
            #pragma unroll
            for (int i = 0; i < 4; ++i) {
                const int row = bm + a * 64 + ty * 4 + i;
                float4 fv = *(const float4*)(F + (size_t)row * N + col);
                const float* fvp = &fv.x;
                float4 o;
                float* op = &o.x;
                bool fl = false;
                #pragma unroll
                for (int j = 0; j < 4; ++j) {
                    float z = acc[a][b][i][j] + bip[j];
                    float gw = 1.0f / (1.0f + __expf(-z));
                    float g = fvp[j] * gw;
                    float c = (g > 0.3f) ? 0.f : g;
                    if (fabsf(g - 0.3f) < B03) fl = true;          // comp-zeroing boundary
                    if (fabsf(fabsf(c) - 0.1f) < B01) fl = true;   // sparsity-count boundary
                    op[j] = c;
                }
                if (fl) flags[row] = 1u;
                *(float4*)(out + (size_t)row * N + col) = o;
            }
        }
    }
}

// ---------------------------------------------------------------------------
// K3: per-row finalize (in-place on d_out).  One WAVE per row, butterfly
// reductions, no barriers.  Per-element math fp32; wave-uniform thr-MLP in
// fp64 (cheap: one exp per wave).  Flags rows with |dyn| within BDYN of thr.
// ---------------------------------------------------------------------------
__global__ __launch_bounds__(256) void finalize_rows(
    float* __restrict__ C,
    const float* __restrict__ wr1, const float* __restrict__ br1,
    const float* __restrict__ wr2, const float* __restrict__ br2,
    const float* __restrict__ wm1, const float* __restrict__ bm1,
    const float* __restrict__ wm2, const float* __restrict__ bm2,
    unsigned* __restrict__ flags)
{
    const int D = 1024;
    const int tid = threadIdx.x;
    const int lane = tid & 63;
    const unsigned row = blockIdx.x * 4 + (tid >> 6);
    const size_t base = (size_t)row * D;
    const int col0 = lane * 4;

    float4 c4[4];
    #pragma unroll
    for (int q = 0; q < 4; ++q)
        c4[q] = *(const float4*)(C + base + q * 256 + col0);

    float c[16];
    #pragma unroll
    for (int q = 0; q < 4; ++q) {
        c[q * 4 + 0] = c4[q].x; c[q * 4 + 1] = c4[q].y;
        c[q * 4 + 2] = c4[q].z; c[q * 4 + 3] = c4[q].w;
    }

    // current sparsity (count is exact integer in fp32)
    float cnt = 0.f;
    #pragma unroll
    for (int i = 0; i < 16; ++i) cnt += (fabsf(c[i]) < 0.1f) ? 1.f : 0.f;
    #pragma unroll
    for (int o = 32; o > 0; o >>= 1) cnt += __shfl_xor(cnt, o, 64);
    const double cur_sp = (double)cnt / 1024.0;   // exact (division by 2^10)

    // sparsity_feedback hidden layer — fp64 (wave-uniform, cheap), then fp32 copy
    float hid[16];
    #pragma unroll
    for (int h = 0; h < 16; ++h) {
        double z = cur_sp * (double)wr1[h] + 0.1 * (double)wr1[16 + h] + (double)br1[h];
        hid[h] = (float)((z > 0.0) ? z : 0.0);
    }

    // dyn = comp * sigmoid(hid @ wr2 + br2)  — fp32
    float dyn[16];
    #pragma unroll
    for (int q = 0; q < 4; ++q) {
        const int cq = q * 256 + col0;
        float4 b4 = *(const float4*)(br2 + cq);
        float z[4] = {b4.x, b4.y, b4.z, b4.w};
        #pragma unroll
        for (int h = 0; h < 16; ++h) {
            float4 w4 = *(const float4*)(wr2 + (size_t)h * D + cq);
            z[0] = fmaf(hid[h], w4.x, z[0]);
            z[1] = fmaf(hid[h], w4.y, z[1]);
            z[2] = fmaf(hid[h], w4.z, z[2]);
            z[3] = fmaf(hid[h], w4.w, z[3]);
        }
        #pragma unroll
        for (int j = 0; j < 4; ++j) {
            float rw = 1.0f / (1.0f + __expf(-z[j]));
            dyn[q * 4 + j] = c[q * 4 + j] * rw;
        }
    }

    // row stats (fp32 butterflies)
    float s = 0.f, mx = -1e30f;
    #pragma unroll
    for (int i = 0; i < 16; ++i) { s += dyn[i]; mx = fmaxf(mx, dyn[i]); }
    #pragma unroll
    for (int o = 32; o > 0; o >>= 1) s += __shfl_xor(s, o, 64);
    const float mean = s / 1024.0f;

    float sq = 0.f;
    #pragma unroll
    for (int i = 0; i < 16; ++i) { float d = dyn[i] - mean; sq = fmaf(d, d, sq); }
    #pragma unroll
    for (int o = 32; o > 0; o >>= 1) sq += __shfl_xor(sq, o, 64);
    const float sd = sqrtf(sq / 1023.0f);

    #pragma unroll
    for (int o = 32; o > 0; o >>= 1) mx = fmaxf(mx, __shfl_xor(mx, o, 64));

    // adaptive threshold — fp64 MLP (wave-uniform; one exp per wave)
    double acc2 = (double)bm2[0];
    #pragma unroll
    for (int h = 0; h < 16; ++h) {
        double hz = (double)mean * (double)wm1[h] + (double)sd * (double)wm1[16 + h]
                  + (double)mx * (double)wm1[32 + h] + (double)bm1[h];
        hz = (hz > 0.0) ? hz : 0.0;
        acc2 += hz * (double)wm2[h];
    }
    const float thr = (float)(1.0 / (1.0 + exp(-acc2)));

    bool fl = false;
    #pragma unroll
    for (int q = 0; q < 4; ++q) {
        float4 o4;
        float* op = &o4.x;
        #pragma unroll
        for (int j = 0; j < 4; ++j) {
            float d = dyn[q * 4 + j];
            float ad = fabsf(d);
            if (fabsf(ad - thr) < BDYN) fl = true;                 // mask boundary
            op[j] = (ad > thr) ? d : 0.f;
        }
        *(float4*)(C + base + q * 256 + col0) = o4;
    }
    if (fl) flags[row] = 1u;
}

// ---------------------------------------------------------------------------
// fp64 block reduction helper (256 threads).
// ---------------------------------------------------------------------------
__device__ __forceinline__ double block_reduce_d(double v, double* sm, int tid, int op)
{
    #pragma unroll
    for (int o = 32; o > 0; o >>= 1) {
        double other = __shfl_down(v, o, 64);
        v = op ? fmax(v, other) : (v + other);
    }
    if ((tid & 63) == 0) sm[tid >> 6] = v;
    __syncthreads();
    if (tid == 0) {
        double r = sm[0];
        for (int w = 1; w < 4; ++w) r = op ? fmax(r, sm[w]) : (r + sm[w]);
        sm[4] = r;
    }
    __syncthreads();
    double r = sm[4];
    __syncthreads();
    return r;
}

// ---------------------------------------------------------------------------
// row_exact: for flagged rows, recompute the ENTIRE pipeline in fp64
// (h1 -> z2 -> comp -> cur_sp -> rw -> dyn -> stats -> thr -> mask),
// matching the np fp64 reference to ~1e-15, and overwrite the output row.
// One block per row; unflagged blocks exit immediately.
// ---------------------------------------------------------------------------
__global__ __launch_bounds__(256) void row_exact(
    const float* __restrict__ F,
    const float* __restrict__ wg1, const float* __restrict__ bg1,
    const float* __restrict__ wg2, const float* __restrict__ bg2,
    const float* __restrict__ wr1, const float* __restrict__ br1,
    const float* __restrict__ wr2, const float* __restrict__ br2,
    const float* __restrict__ wm1, const float* __restrict__ bm1,
    const float* __restrict__ wm2, const float* __restrict__ bm2,
    const unsigned* __restrict__ flags, float* __restrict__ out)
{
    const unsigned row = blockIdx.x;
    if (flags[row] == 0u) return;

    __shared__ float  Fs[1024];
    __shared__ double h1d[256];
    __shared__ double sm[8];
    const int tid = threadIdx.x;

    *(float4*)&Fs[tid * 4] = *(const float4*)(F + (size_t)row * 1024 + tid * 4);
    __syncthreads();

    // h1[tid] = relu(F[row,:] . Wg1[:,tid] + b1[tid])  (fp64)
    double a = 0.0;
    #pragma unroll 4
    for (int j = 0; j < 1024; ++j)
        a += (double)Fs[j] * (double)wg1[(size_t)j * 256 + tid];
    a += (double)bg1[tid];
    h1d[tid] = (a > 0.0) ? a : 0.0;
    __syncthreads();

    // comp for cols 4t..4t+3 (fp64)
    const int c0 = tid * 4;
    double z[4] = {(double)bg2[c0], (double)bg2[c0 + 1],
                   (double)bg2[c0 + 2], (double)bg2[c0 + 3]};
    #pragma unroll 4
    for (int j = 0; j < 256; ++j) {
        float4 w = *(const float4*)(wg2 + (size_t)j * 1024 + c0);
        double h = h1d[j];
        z[0] += h * (double)w.x; z[1] += h * (double)w.y;
        z[2] += h * (double)w.z; z[3] += h * (double)w.w;
    }
    double comp[4];
    double cnt = 0.0;
    #pragma unroll
    for (int j = 0; j < 4; ++j) {
        double gw = 1.0 / (1.0 + exp(-z[j]));
        double g = (double)Fs[c0 + j] * gw;
        double cm = (g > 0.3) ? 0.0 : g;
        comp[j] = cm;
        cnt += (fabs(cm) < 0.1) ? 1.0 : 0.0;
    }
    cnt = block_reduce_d(cnt, sm, tid, 0);
    const double cur_sp = cnt / 1024.0;

    // sparsity_feedback (fp64)
    double hid[16];
    #pragma unroll
    for (int h = 0; h < 16; ++h) {
        double hz = cur_sp * (double)wr1[h] + 0.1 * (double)wr1[16 + h] + (double)br1[h];
        hid[h] = (hz > 0.0) ? hz : 0.0;
    }
    double zr[4] = {(double)br2[c0], (double)br2[c0 + 1],
                    (double)br2[c0 + 2], (double)br2[c0 + 3]};
    #pragma unroll
    for (int h = 0; h < 16; ++h) {
        float4 w4 = *(const float4*)(wr2 + (size_t)h * 1024 + c0);
        zr[0] += hid[h] * (double)w4.x; zr[1] += hid[h] * (double)w4.y;
        zr[2] += hid[h] * (double)w4.z; zr[3] += hid[h] * (double)w4.w;
    }
    double dyn[4];
    #pragma unroll
    for (int j = 0; j < 4; ++j) {
        double rw = 1.0 / (1.0 + exp(-zr[j]));
        dyn[j] = comp[j] * rw;
    }

    // stats (fp64)
    double s = dyn[0] + dyn[1] + dyn[2] + dyn[3];
    s = block_reduce_d(s, sm, tid, 0);
    const double mean = s / 1024.0;

    double sq = 0.0;
    #pragma unroll
    for (int j = 0; j < 4; ++j) { double d = dyn[j] - mean; sq += d * d; }
    sq = block_reduce_d(sq, sm, tid, 0);
    const double sd = sqrt(sq / 1023.0);

    double mx = fmax(fmax(dyn[0], dyn[1]), fmax(dyn[2], dyn[3]));
    mx = block_reduce_d(mx, sm, tid, 1);

    // adaptive threshold (fp64)
    double acc2 = (double)bm2[0];
    #pragma unroll
    for (int h = 0; h < 16; ++h) {
        double hz = mean * (double)wm1[h] + sd * (double)wm1[16 + h]
                  + mx * (double)wm1[32 + h] + (double)bm1[h];
        hz = (hz > 0.0) ? hz : 0.0;
        acc2 += hz * (double)wm2[h];
    }
    const double thr = 1.0 / (1.0 + exp(-acc2));

    float4 o4;
    o4.x = (float)((fabs(dyn[0]) > thr) ? dyn[0] : 0.0);
    o4.y = (float)((fabs(dyn[1]) > thr) ? dyn[1] : 0.0);
    o4.z = (float)((fabs(dyn[2]) > thr) ? dyn[2] : 0.0);
    o4.w = (float)((fabs(dyn[3]) > thr) ? dyn[3] : 0.0);
    *(float4*)(out + (size_t)row * 1024 + c0) = o4;
}

// ---------------------------------------------------------------------------
extern "C" void kernel_launch(void* const* d_in, const int* in_sizes, int n_in,
                              void* d_out, int out_size, void* d_ws, size_t ws_size,
                              hipStream_t stream)
{
    const float* F   = (const float*)d_in[0];
    const float* wg1 = (const float*)d_in[1];
    const float* bg1 = (const float*)d_in[2];
    const float* wg2 = (const float*)d_in[3];
    const float* bg2 = (const float*)d_in[4];
    // d_in[5..8]: competition calculator — provably dead (win == False always)
    const float* wr1 = (const float*)d_in[9];
    const float* br1 = (const float*)d_in[10];
    const float* wr2 = (const float*)d_in[11];
    const float* br2 = (const float*)d_in[12];
    const float* wm1 = (const float*)d_in[13];
    const float* bm1 = (const float*)d_in[14];
    const float* wm2 = (const float*)d_in[15];
    const float* bm2 = (const float*)d_in[16];

    float* out = (float*)d_out;
    const int M = in_sizes[0] / 1024;                      // 32768

    float*    h1    = (float*)d_ws;                        // 32 MiB
    unsigned* flags = (unsigned*)((char*)d_ws + (32u << 20));  // 128 KiB

    hipMemsetAsync(flags, 0, (size_t)M * sizeof(unsigned), stream);
    gemm1_f32<<<dim3(M / TM, 256 / TN), 256, 0, stream>>>(F, wg1, bg1, h1, M);
    gemm2_f32<<<dim3(M / TM, 1024 / TN), 256, 0, stream>>>(h1, wg2, bg2, F, out, flags, M);
    finalize_rows<<<M / 4, 256, 0, stream>>>(out, wr1, br1, wr2, br2, wm1, bm1, wm2, bm2, flags);
    row_exact<<<M, 256, 0, stream>>>(F, wg1, bg1, wg2, bg2, wr1, br1, wr2, br2,
                                     wm1, bm1, wm2, bm2, flags, out);
}

// Round 5
// 1255.980 us; speedup vs baseline: 1.3886x; 1.3886x over previous
//
#include <hip/hip_runtime.h>
#include <cmath>

#define TM 128
#define TN 128
#define TK 16
#define LDSW 132          // padded LDS row width (floats)
#define FIXCAP 262144u
#define ROWCAP 32768u

// Decision-boundary protection bands.
// Fast-path error (fp32 tiled acc + __expf sigmoid) vs fp64 np reference:
// typical ~2e-7, 33.5M-sample tail ~1.5e-6.  Bands give >=16x margin.
#define B03  2.5e-5f      // g vs 0.3            -> element fix (tier 1)
#define B01  2.5e-5f      // |comp| vs 0.1       -> element fix (tier 1)
#define B2   5e-6         // tier-1 residual band -> tier-2 full fp64 fix
#define BDYN 3e-5f        // |dyn| vs thr        -> row fp64 redo (row_exact)

// ---------------------------------------------------------------------------
// Shared 128x128x16 fp32 tile mainloop (validated rounds 2/3).  Double-
// buffered LDS ping-pong, one barrier per K-step, bitwise-stable acc order.
// ---------------------------------------------------------------------------
#define STAGE_STORE(B)                                                          \
        As[B][aq * 4 + 0][ar] = pa0.x; As[B][aq * 4 + 1][ar] = pa0.y;           \
        As[B][aq * 4 + 2][ar] = pa0.z; As[B][aq * 4 + 3][ar] = pa0.w;           \
        As[B][aq * 4 + 0][ar + 64] = pa1.x; As[B][aq * 4 + 1][ar + 64] = pa1.y; \
        As[B][aq * 4 + 2][ar + 64] = pa1.z; As[B][aq * 4 + 3][ar + 64] = pa1.w; \
        *(float4*)&Bs[B][bk][bn4] = pb0;                                        \
        *(float4*)&Bs[B][bk + 8][bn4] = pb1;

#define GEMM_MAINLOOP(Aptr, Wptr, Kdim, Ndim)                                   \
    __shared__ float As[2][TK][LDSW];                                           \
    __shared__ float Bs[2][TK][LDSW];                                           \
    const int tid = threadIdx.x;                                                \
    const int bm = blockIdx.x * TM;                                             \
    const int bn = blockIdx.y * TN;                                             \
    const int tx = tid & 15, ty = tid >> 4;                                     \
    const int ar = tid >> 2, aq = tid & 3;                                      \
    const int bk = tid >> 5, bn4 = (tid & 31) * 4;                              \
    float acc[2][2][4][4];                                                      \
    _Pragma("unroll") for (int a = 0; a < 2; ++a)                               \
    _Pragma("unroll") for (int b = 0; b < 2; ++b)                               \
    _Pragma("unroll") for (int i = 0; i < 4; ++i)                               \
    _Pragma("unroll") for (int j = 0; j < 4; ++j) acc[a][b][i][j] = 0.f;        \
    float4 pa0 = *(const float4*)((Aptr) + (size_t)(bm + ar) * (Kdim) + aq * 4);      \
    float4 pa1 = *(const float4*)((Aptr) + (size_t)(bm + ar + 64) * (Kdim) + aq * 4); \
    float4 pb0 = *(const float4*)((Wptr) + (size_t)bk * (Ndim) + bn + bn4);           \
    float4 pb1 = *(const float4*)((Wptr) + (size_t)(bk + 8) * (Ndim) + bn + bn4);     \
    STAGE_STORE(0)                                                              \
    __syncthreads();                                                            \
    int buf = 0;                                                                \
    for (int k0 = 0; k0 < (Kdim); k0 += TK) {                                   \
        const int nk = k0 + TK;                                                 \
        if (nk < (Kdim)) {                                                      \
            pa0 = *(const float4*)((Aptr) + (size_t)(bm + ar) * (Kdim) + nk + aq * 4);      \
            pa1 = *(const float4*)((Aptr) + (size_t)(bm + ar + 64) * (Kdim) + nk + aq * 4); \
            pb0 = *(const float4*)((Wptr) + (size_t)(nk + bk) * (Ndim) + bn + bn4);         \
            pb1 = *(const float4*)((Wptr) + (size_t)(nk + bk + 8) * (Ndim) + bn + bn4);     \
        }                                                                       \
        _Pragma("unroll") for (int k = 0; k < TK; ++k) {                        \
            float4 da0 = *(const float4*)&As[buf][k][ty * 4];                   \
            float4 da1 = *(const float4*)&As[buf][k][64 + ty * 4];              \
            float4 db0 = *(const float4*)&Bs[buf][k][tx * 4];                   \
            float4 db1 = *(const float4*)&Bs[buf][k][64 + tx * 4];              \
            const float* dap[2] = {&da0.x, &da1.x};                             \
            const float* dbp[2] = {&db0.x, &db1.x};                             \
            _Pragma("unroll") for (int a = 0; a < 2; ++a)                       \
            _Pragma("unroll") for (int b = 0; b < 2; ++b)                       \
            _Pragma("unroll") for (int i = 0; i < 4; ++i)                       \
            _Pragma("unroll") for (int j = 0; j < 4; ++j)                       \
                acc[a][b][i][j] = fmaf(dap[a][i], dbp[b][j], acc[a][b][i][j]);  \
        }                                                                       \
        if (nk < (Kdim)) {                                                      \
            const int nb = buf ^ 1;                                             \
            STAGE_STORE(nb)                                                     \
            __syncthreads();                                                    \
            buf = nb;                                                           \
        }                                                                       \
    }

// ---------------------------------------------------------------------------
// K1: h1 = relu(F @ Wg1 + b1), fp32.
// ---------------------------------------------------------------------------
__global__ __launch_bounds__(256) void gemm1_f32(
    const float* __restrict__ A, const float* __restrict__ W,
    const float* __restrict__ bias, float* __restrict__ out, int M)
{
    const int K = 1024, N = 256;
    GEMM_MAINLOOP(A, W, K, N)
    #pragma unroll
    for (int a = 0; a < 2; ++a) {
        #pragma unroll
        for (int b = 0; b < 2; ++b) {
            const int col = bn + b * 64 + tx * 4;
            float4 bi = *(const float4*)(bias + col);
            #pragma unroll
            for (int i = 0; i < 4; ++i) {
                const int row = bm + a * 64 + ty * 4 + i;
                float4 o;
                o.x = fmaxf(acc[a][b][i][0] + bi.x, 0.f);
                o.y = fmaxf(acc[a][b][i][1] + bi.y, 0.f);
                o.z = fmaxf(acc[a][b][i][2] + bi.z, 0.f);
                o.w = fmaxf(acc[a][b][i][3] + bi.w, 0.f);
                *(float4*)(out + (size_t)row * N + col) = o;
            }
        }
    }
}

// ---------------------------------------------------------------------------
// K2: z2 = h1 @ Wg2 + b2; g = F * sigmoid(z2); comp = (g>0.3)?0:g.
// fp32 epilogue.  Near-boundary elements -> elist1 for the tiered fp64 fix.
// ---------------------------------------------------------------------------
__global__ __launch_bounds__(256) void gemm2_f32(
    const float* __restrict__ A, const float* __restrict__ W,
    const float* __restrict__ bias, const float* __restrict__ F,
    float* __restrict__ out, unsigned* __restrict__ ectr1,
    uint2* __restrict__ elist1, int M)
{
    const int K = 256, N = 1024;
    GEMM_MAINLOOP(A, W, K, N)
    #pragma unroll
    for (int a = 0; a < 2; ++a) {
        #pragma unroll
        for (int b = 0; b < 2; ++b) {
            const int col = bn + b * 64 + tx * 4;
            float4 bi = *(const float4*)(bias + col);
            const float* bip = &bi.x;
            #pragma unroll
            for (int i = 0; i < 4; ++i) {
                const int row = bm + a * 64 + ty * 4 + i;
                float4 fv = *(const float4*)(F + (size_t)row * N + col);
                const float* fvp = &fv.x;
                float4 o;
                float* op = &o.x;
                #pragma unroll
                for (int j = 0; j < 4; ++j) {
                    float z = acc[a][b][i][j] + bip[j];
                    float gw = 1.0f / (1.0f + __expf(-z));
                    float g = fvp[j] * gw;
                    float c = (g > 0.3f) ? 0.f : g;
                    if (fabsf(g - 0.3f) < B03 || fabsf(fabsf(c) - 0.1f) < B01) {
                        unsigned idx = atomicAdd(ectr1, 1u);
                        if (idx < FIXCAP) elist1[idx] = make_uint2((unsigned)row, (unsigned)(col + j));
                    }
                    op[j] = c;
                }
                *(float4*)(out + (size_t)row * N + col) = o;
            }
        }
    }
}

// ---------------------------------------------------------------------------
// fix_near (tier 1): refine flagged elements with an fp64 dot of the STORED
// fp32 h1 row and the Wg2 column (error vs fp64 ref <= ~2e-6).  Elements
// still within B2 of a boundary escalate to fix_full.  Otherwise write the
// refined value and adjust the per-row sparsity-count correction so the
// count decision matches the fp64 reference exactly.
// ---------------------------------------------------------------------------
__global__ __launch_bounds__(256) void fix_near(
    const float* __restrict__ h1, const float* __restrict__ F,
    const float* __restrict__ Wg2, const float* __restrict__ bg2,
    const unsigned* __restrict__ ectr1, const uint2* __restrict__ elist1,
    unsigned* __restrict__ ectr2, uint2* __restrict__ elist2,
    float* __restrict__ out, int* __restrict__ corr)
{
    __shared__ double red[4];
    const int tid = threadIdx.x;
    unsigned cnt = *ectr1;
    if (cnt > FIXCAP) cnt = FIXCAP;

    for (unsigned e = blockIdx.x; e < cnt; e += gridDim.x) {
        const unsigned row = elist1[e].x, col = elist1[e].y;
        double p = (double)h1[(size_t)row * 256 + tid]
                 * (double)Wg2[(size_t)tid * 1024 + col];
        #pragma unroll
        for (int o = 32; o > 0; o >>= 1) p += __shfl_down(p, o, 64);
        if ((tid & 63) == 0) red[tid >> 6] = p;
        __syncthreads();
        if (tid == 0) {
            double z2 = red[0] + red[1] + red[2] + red[3] + (double)bg2[col];
            double gw = 1.0 / (1.0 + exp(-z2));
            double g = (double)F[(size_t)row * 1024 + col] * gw;
            double c = (g > 0.3) ? 0.0 : g;
            bool near = (fabs(g - 0.3) < B2) || (fabs(fabs(c) - 0.1) < B2);
            if (near) {
                unsigned i2 = atomicAdd(ectr2, 1u);
                if (i2 < FIXCAP) elist2[i2] = make_uint2(row, col);
            } else {
                float cf = (float)c;
                int d_ref = (fabs(c) < 0.1) ? 1 : 0;
                int d_st  = (fabsf(cf) < 0.1f) ? 1 : 0;
                if (d_ref != d_st) atomicAdd(&corr[row], d_ref - d_st);
                out[(size_t)row * 1024 + col] = cf;
            }
        }
        __syncthreads();
    }
}

// ---------------------------------------------------------------------------
// fix_full (tier 2): true fp64 recompute from F (h1 fp64 -> z2 fp64) for the
// few elements too close for tier 1.  Same count-correction mechanism.
// ---------------------------------------------------------------------------
__global__ __launch_bounds__(256) void fix_full(
    const float* __restrict__ F, const float* __restrict__ Wg1,
    const float* __restrict__ bg1, const float* __restrict__ Wg2,
    const float* __restrict__ bg2,
    const unsigned* __restrict__ ectr2, const uint2* __restrict__ elist2,
    float* __restrict__ out, int* __restrict__ corr)
{
    __shared__ float Fs[1024];
    __shared__ double red[4];
    const int tid = threadIdx.x;
    unsigned cnt = *ectr2;
    if (cnt > FIXCAP) cnt = FIXCAP;

    for (unsigned e = blockIdx.x; e < cnt; e += gridDim.x) {
        const unsigned row = elist2[e].x, col = elist2[e].y;
        __syncthreads();
        *(float4*)&Fs[tid * 4] = *(const float4*)(F + (size_t)row * 1024 + tid * 4);
        __syncthreads();
        double pa[8];
        #pragma unroll
        for (int u = 0; u < 8; ++u) pa[u] = 0.0;
        for (int j = 0; j < 1024; j += 8) {
            #pragma unroll
            for (int u = 0; u < 8; ++u)
                pa[u] += (double)Fs[j + u] * (double)Wg1[(size_t)(j + u) * 256 + tid];
        }
        double a = ((pa[0] + pa[1]) + (pa[2] + pa[3])) + ((pa[4] + pa[5]) + (pa[6] + pa[7]));
        double h = a + (double)bg1[tid];
        h = (h > 0.0) ? h : 0.0;
        double p = h * (double)Wg2[(size_t)tid * 1024 + col];
        #pragma unroll
        for (int o = 32; o > 0; o >>= 1) p += __shfl_down(p, o, 64);
        if ((tid & 63) == 0) red[tid >> 6] = p;
        __syncthreads();
        if (tid == 0) {
            double z2 = red[0] + red[1] + red[2] + red[3] + (double)bg2[col];
            double gw = 1.0 / (1.0 + exp(-z2));
            double g = (double)Fs[col] * gw;
            double c = (g > 0.3) ? 0.0 : g;
            float cf = (float)c;
            int d_ref = (fabs(c) < 0.1) ? 1 : 0;
            int d_st  = (fabsf(cf) < 0.1f) ? 1 : 0;
            if (d_ref != d_st) atomicAdd(&corr[row], d_ref - d_st);
            out[(size_t)row * 1024 + col] = cf;
        }
    }
}

// ---------------------------------------------------------------------------
// K3: per-row finalize (in-place on d_out).  One WAVE per row, fp32 fast
// path, sparsity count adjusted by corr[] so cur_sp matches the fp64 ref
// exactly.  Rows with any |dyn| within BDYN of thr skip the store and go to
// row_exact (full fp64 redo from F -- the round-3-validated path).
// ---------------------------------------------------------------------------
__global__ __launch_bounds__(256) void finalize_rows(
    float* __restrict__ C,
    const float* __restrict__ wr1, const float* __restrict__ br1,
    const float* __restrict__ wr2, const float* __restrict__ br2,
    const float* __restrict__ wm1, const float* __restrict__ bm1,
    const float* __restrict__ wm2, const float* __restrict__ bm2,
    const int* __restrict__ corr,
    unsigned* __restrict__ rctr, unsigned* __restrict__ rowlist)
{
    const int D = 1024;
    const int tid = threadIdx.x;
    const int lane = tid & 63;
    const unsigned row = blockIdx.x * 4 + (tid >> 6);
    const size_t base = (size_t)row * D;
    const int col0 = lane * 4;

    float4 c4[4];
    #pragma unroll
    for (int q = 0; q < 4; ++q)
        c4[q] = *(const float4*)(C + base + q * 256 + col0);

    float c[16];
    #pragma unroll
    for (int q = 0; q < 4; ++q) {
        c[q * 4 + 0] = c4[q].x; c[q * 4 + 1] = c4[q].y;
        c[q * 4 + 2] = c4[q].z; c[q * 4 + 3] = c4[q].w;
    }

    // current sparsity (integer-exact, ref-matched via corr)
    float cnt = 0.f;
    #pragma unroll
    for (int i = 0; i < 16; ++i) cnt += (fabsf(c[i]) < 0.1f) ? 1.f : 0.f;
    #pragma unroll
    for (int o = 32; o > 0; o >>= 1) cnt += __shfl_xor(cnt, o, 64);
    cnt += (float)corr[row];
    const double cur_sp = (double)cnt / 1024.0;   // exact

    // sparsity_feedback hidden layer (fp64, wave-uniform)
    float hid[16];
    #pragma unroll
    for (int h = 0; h < 16; ++h) {
        double z = cur_sp * (double)wr1[h] + 0.1 * (double)wr1[16 + h] + (double)br1[h];
        hid[h] = (float)((z > 0.0) ? z : 0.0);
    }

    // dyn = comp * sigmoid(hid @ wr2 + br2)  (fp32)
    float dyn[16];
    #pragma unroll
    for (int q = 0; q < 4; ++q) {
        const int cq = q * 256 + col0;
        float4 b4 = *(const float4*)(br2 + cq);
        float z[4] = {b4.x, b4.y, b4.z, b4.w};
        #pragma unroll
        for (int h = 0; h < 16; ++h) {
            float4 w4 = *(const float4*)(wr2 + (size_t)h * D + cq);
            z[0] = fmaf(hid[h], w4.x, z[0]);
            z[1] = fmaf(hid[h], w4.y, z[1]);
            z[2] = fmaf(hid[h], w4.z, z[2]);
            z[3] = fmaf(hid[h], w4.w, z[3]);
        }
        #pragma unroll
        for (int j = 0; j < 4; ++j) {
            float rw = 1.0f / (1.0f + __expf(-z[j]));
            dyn[q * 4 + j] = c[q * 4 + j] * rw;
        }
    }

    // row stats (fp32 butterflies)
    float s = 0.f, mx = -1e30f;
    #pragma unroll
    for (int i = 0; i < 16; ++i) { s += dyn[i]; mx = fmaxf(mx, dyn[i]); }
    #pragma unroll
    for (int o = 32; o > 0; o >>= 1) s += __shfl_xor(s, o, 64);
    const float mean = s / 1024.0f;

    float sq = 0.f;
    #pragma unroll
    for (int i = 0; i < 16; ++i) { float d = dyn[i] - mean; sq = fmaf(d, d, sq); }
    #pragma unroll
    for (int o = 32; o > 0; o >>= 1) sq += __shfl_xor(sq, o, 64);
    const float sd = sqrtf(sq / 1023.0f);

    #pragma unroll
    for (int o = 32; o > 0; o >>= 1) mx = fmaxf(mx, __shfl_xor(mx, o, 64));

    // adaptive threshold (fp64 MLP, wave-uniform)
    double acc2 = (double)bm2[0];
    #pragma unroll
    for (int h = 0; h < 16; ++h) {
        double hz = (double)mean * (double)wm1[h] + (double)sd * (double)wm1[16 + h]
                  + (double)mx * (double)wm1[32 + h] + (double)bm1[h];
        hz = (hz > 0.0) ? hz : 0.0;
        acc2 += hz * (double)wm2[h];
    }
    const float thr = (float)(1.0 / (1.0 + exp(-acc2)));

    bool fl = false;
    #pragma unroll
    for (int i = 0; i < 16; ++i)
        if (fabsf(fabsf(dyn[i]) - thr) < BDYN) fl = true;

    if (__any(fl)) {
        if (lane == 0) {
            unsigned idx = atomicAdd(rctr, 1u);
            if (idx < ROWCAP) rowlist[idx] = row;
        }
        return;                         // preserve comp row for row_exact
    }

    #pragma unroll
    for (int q = 0; q < 4; ++q) {
        float4 o4;
        float* op = &o4.x;
        #pragma unroll
        for (int j = 0; j < 4; ++j) {
            float d = dyn[q * 4 + j];
            op[j] = (fabsf(d) > thr) ? d : 0.f;
        }
        *(float4*)(C + base + q * 256 + col0) = o4;
    }
}

// ---------------------------------------------------------------------------
// fp64 block reduction helper (256 threads).
// ---------------------------------------------------------------------------
__device__ __forceinline__ double block_reduce_d(double v, double* sm, int tid, int op)
{
    #pragma unroll
    for (int o = 32; o > 0; o >>= 1) {
        double other = __shfl_down(v, o, 64);
        v = op ? fmax(v, other) : (v + other);
    }
    if ((tid & 63) == 0) sm[tid >> 6] = v;
    __syncthreads();
    if (tid == 0) {
        double r = sm[0];
        for (int w = 1; w < 4; ++w) r = op ? fmax(r, sm[w]) : (r + sm[w]);
        sm[4] = r;
    }
    __syncthreads();
    double r = sm[4];
    __syncthreads();
    return r;
}

// ---------------------------------------------------------------------------
// row_exact (round-3-VALIDATED math): full fp64 recompute of the ENTIRE
// pipeline from F for rows near the mask boundary.  This is the only path
// proven to resolve ~1e-8-tight |dyn|-thr decisions against the fp64 ref.
// ---------------------------------------------------------------------------
__global__ __launch_bounds__(256) void row_exact(
    const float* __restrict__ F,
    const float* __restrict__ wg1, const float* __restrict__ bg1,
    const float* __restrict__ wg2, const float* __restrict__ bg2,
    const float* __restrict__ wr1, const float* __restrict__ br1,
    const float* __restrict__ wr2, const float* __restrict__ br2,
    const float* __restrict__ wm1, const float* __restrict__ bm1,
    const float* __restrict__ wm2, const float* __restrict__ bm2,
    const unsigned* __restrict__ rctr, const unsigned* __restrict__ rowlist,
    float* __restrict__ out)
{
    __shared__ float  Fs[1024];
    __shared__ double h1d[256];
    __shared__ double sm[8];
    const int tid = threadIdx.x;
    unsigned rcnt = *rctr;
    if (rcnt > ROWCAP) rcnt = ROWCAP;

    for (unsigned e = blockIdx.x; e < rcnt; e += gridDim.x) {
        const unsigned row = rowlist[e];
        __syncthreads();
        *(float4*)&Fs[tid * 4] = *(const float4*)(F + (size_t)row * 1024 + tid * 4);
        __syncthreads();

        double a = 0.0;
        #pragma unroll 4
        for (int j = 0; j < 1024; ++j)
            a += (double)Fs[j] * (double)wg1[(size_t)j * 256 + tid];
        a += (double)bg1[tid];
        h1d[tid] = (a > 0.0) ? a : 0.0;
        __syncthreads();

        const int c0 = tid * 4;
        double z[4] = {(double)bg2[c0], (double)bg2[c0 + 1],
                       (double)bg2[c0 + 2], (double)bg2[c0 + 3]};
        #pragma unroll 4
        for (int j = 0; j < 256; ++j) {
            float4 w = *(const float4*)(wg2 + (size_t)j * 1024 + c0);
            double h = h1d[j];
            z[0] += h * (double)w.x; z[1] += h * (double)w.y;
            z[2] += h * (double)w.z; z[3] += h * (double)w.w;
        }
        double comp[4];
        double cnt = 0.0;
        #pragma unroll
        for (int j = 0; j < 4; ++j) {
            double gw = 1.0 / (1.0 + exp(-z[j]));
            double g = (double)Fs[c0 + j] * gw;
            double cm = (g > 0.3) ? 0.0 : g;
            comp[j] = cm;
            cnt += (fabs(cm) < 0.1) ? 1.0 : 0.0;
        }
        cnt = block_reduce_d(cnt, sm, tid, 0);
        const double cur_sp = cnt / 1024.0;

        double hid[16];
        #pragma unroll
        for (int h = 0; h < 16; ++h) {
            double hz = cur_sp * (double)wr1[h] + 0.1 * (double)wr1[16 + h] + (double)br1[h];
            hid[h] = (hz > 0.0) ? hz : 0.0;
        }
        double zr[4] = {(double)br2[c0], (double)br2[c0 + 1],
                        (double)br2[c0 + 2], (double)br2[c0 + 3]};
        #pragma unroll
        for (int h = 0; h < 16; ++h) {
            float4 w4 = *(const float4*)(wr2 + (size_t)h * 1024 + c0);
            zr[0] += hid[h] * (double)w4.x; zr[1] += hid[h] * (double)w4.y;
            zr[2] += hid[h] * (double)w4.z; zr[3] += hid[h] * (double)w4.w;
        }
        double dyn[4];
        #pragma unroll
        for (int j = 0; j < 4; ++j) {
            double rw = 1.0 / (1.0 + exp(-zr[j]));
            dyn[j] = comp[j] * rw;
        }

        double s = dyn[0] + dyn[1] + dyn[2] + dyn[3];
        s = block_reduce_d(s, sm, tid, 0);
        const double mean = s / 1024.0;

        double sq = 0.0;
        #pragma unroll
        for (int j = 0; j < 4; ++j) { double d = dyn[j] - mean; sq += d * d; }
        sq = block_reduce_d(sq, sm, tid, 0);
        const double sd = sqrt(sq / 1023.0);

        double mx = fmax(fmax(dyn[0], dyn[1]), fmax(dyn[2], dyn[3]));
        mx = block_reduce_d(mx, sm, tid, 1);

        double acc2 = (double)bm2[0];
        #pragma unroll
        for (int h = 0; h < 16; ++h) {
            double hz = mean * (double)wm1[h] + sd * (double)wm1[16 + h]
                      + mx * (double)wm1[32 + h] + (double)bm1[h];
            hz = (hz > 0.0) ? hz : 0.0;
            acc2 += hz * (double)wm2[h];
        }
        const double thr = 1.0 / (1.0 + exp(-acc2));

        float4 o4;
        o4.x = (float)((fabs(dyn[0]) > thr) ? dyn[0] : 0.0);
        o4.y = (float)((fabs(dyn[1]) > thr) ? dyn[1] : 0.0);
        o4.z = (float)((fabs(dyn[2]) > thr) ? dyn[2] : 0.0);
        o4.w = (float)((fabs(dyn[3]) > thr) ? dyn[3] : 0.0);
        *(float4*)(out + (size_t)row * 1024 + c0) = o4;
    }
}

// ---------------------------------------------------------------------------
extern "C" void kernel_launch(void* const* d_in, const int* in_sizes, int n_in,
                              void* d_out, int out_size, void* d_ws, size_t ws_size,
                              hipStream_t stream)
{
    const float* F   = (const float*)d_in[0];
    const float* wg1 = (const float*)d_in[1];
    const float* bg1 = (const float*)d_in[2];
    const float* wg2 = (const float*)d_in[3];
    const float* bg2 = (const float*)d_in[4];
    // d_in[5..8]: competition calculator — provably dead (win == False always)
    const float* wr1 = (const float*)d_in[9];
    const float* br1 = (const float*)d_in[10];
    const float* wr2 = (const float*)d_in[11];
    const float* br2 = (const float*)d_in[12];
    const float* wm1 = (const float*)d_in[13];
    const float* bm1 = (const float*)d_in[14];
    const float* wm2 = (const float*)d_in[15];
    const float* bm2 = (const float*)d_in[16];

    float* out = (float*)d_out;
    const int M = in_sizes[0] / 1024;                      // 32768

    char* ws = (char*)d_ws;
    float*    h1      = (float*)ws;                              // 32 MiB
    uint2*    elist1  = (uint2*)(ws + (32u << 20));              // 2 MiB
    uint2*    elist2  = (uint2*)(ws + (34u << 20));              // 2 MiB
    unsigned* rowlist = (unsigned*)(ws + (36u << 20));           // 128 KiB
    int*      corr    = (int*)(ws + (36u << 20) + (128u << 10)); // 128 KiB
    unsigned* ctrs    = (unsigned*)(ws + (36u << 20) + (256u << 10));
    unsigned* ectr1 = ctrs, *ectr2 = ctrs + 1, *rctr = ctrs + 2;

    // zero corr + counters in one shot (contiguous)
    hipMemsetAsync(corr, 0, (size_t)M * sizeof(int) + 16, stream);
    gemm1_f32<<<dim3(M / TM, 256 / TN), 256, 0, stream>>>(F, wg1, bg1, h1, M);
    gemm2_f32<<<dim3(M / TM, 1024 / TN), 256, 0, stream>>>(h1, wg2, bg2, F, out, ectr1, elist1, M);
    fix_near<<<2048, 256, 0, stream>>>(h1, F, wg2, bg2, ectr1, elist1, ectr2, elist2, out, corr);
    fix_full<<<1024, 256, 0, stream>>>(F, wg1, bg1, wg2, bg2, ectr2, elist2, out, corr);
    finalize_rows<<<M / 4, 256, 0, stream>>>(out, wr1, br1, wr2, br2, wm1, bm1, wm2, bm2,
                                             corr, rctr, rowlist);
    row_exact<<<2048, 256, 0, stream>>>(F, wg1, bg1, wg2, bg2, wr1, br1, wr2, br2,
                                        wm1, bm1, wm2, bm2, rctr, rowlist, out);
}

// Round 6
// 1210.175 us; speedup vs baseline: 1.4411x; 1.0378x over previous
//
#include <hip/hip_runtime.h>
#include <cmath>

#define TM 128
#define TN 128
#define TK 16
#define LDSW 132          // padded LDS row width (floats)
#define FIXCAP 262144u
#define ROWCAP 32768u

// Decision-boundary protection bands.
// Fast-path error (fp32 tiled acc + __expf sigmoid) vs fp64 np reference:
// typical ~2e-7, 33.5M-sample tail ~1.5e-6.  Bands give >=16x margin.
#define B03  2.5e-5f      // g vs 0.3            -> element fix (tier 1)
#define B01  2.5e-5f      // |comp| vs 0.1       -> element fix (tier 1)
#define B2   5e-6         // tier-1 residual band -> tier-2 full fp64 fix
#define BDYN 3e-5f        // |dyn| vs thr        -> row fp64 redo (row_exact)

// ---------------------------------------------------------------------------
// Shared 128x128x16 fp32 tile mainloop (validated rounds 2/3/5).  Double-
// buffered LDS ping-pong, one barrier per K-step, bitwise-stable acc order.
// ---------------------------------------------------------------------------
#define STAGE_STORE(B)                                                          \
        As[B][aq * 4 + 0][ar] = pa0.x; As[B][aq * 4 + 1][ar] = pa0.y;           \
        As[B][aq * 4 + 2][ar] = pa0.z; As[B][aq * 4 + 3][ar] = pa0.w;           \
        As[B][aq * 4 + 0][ar + 64] = pa1.x; As[B][aq * 4 + 1][ar + 64] = pa1.y; \
        As[B][aq * 4 + 2][ar + 64] = pa1.z; As[B][aq * 4 + 3][ar + 64] = pa1.w; \
        *(float4*)&Bs[B][bk][bn4] = pb0;                                        \
        *(float4*)&Bs[B][bk + 8][bn4] = pb1;

#define GEMM_MAINLOOP(Aptr, Wptr, Kdim, Ndim)                                   \
    __shared__ float As[2][TK][LDSW];                                           \
    __shared__ float Bs[2][TK][LDSW];                                           \
    const int tid = threadIdx.x;                                                \
    const int bm = blockIdx.x * TM;                                             \
    const int bn = blockIdx.y * TN;                                             \
    const int tx = tid & 15, ty = tid >> 4;                                     \
    const int ar = tid >> 2, aq = tid & 3;                                      \
    const int bk = tid >> 5, bn4 = (tid & 31) * 4;                              \
    float acc[2][2][4][4];                                                      \
    _Pragma("unroll") for (int a = 0; a < 2; ++a)                               \
    _Pragma("unroll") for (int b = 0; b < 2; ++b)                               \
    _Pragma("unroll") for (int i = 0; i < 4; ++i)                               \
    _Pragma("unroll") for (int j = 0; j < 4; ++j) acc[a][b][i][j] = 0.f;        \
    float4 pa0 = *(const float4*)((Aptr) + (size_t)(bm + ar) * (Kdim) + aq * 4);      \
    float4 pa1 = *(const float4*)((Aptr) + (size_t)(bm + ar + 64) * (Kdim) + aq * 4); \
    float4 pb0 = *(const float4*)((Wptr) + (size_t)bk * (Ndim) + bn + bn4);           \
    float4 pb1 = *(const float4*)((Wptr) + (size_t)(bk + 8) * (Ndim) + bn + bn4);     \
    STAGE_STORE(0)                                                              \
    __syncthreads();                                                            \
    int buf = 0;                                                                \
    for (int k0 = 0; k0 < (Kdim); k0 += TK) {                                   \
        const int nk = k0 + TK;                                                 \
        if (nk < (Kdim)) {                                                      \
            pa0 = *(const float4*)((Aptr) + (size_t)(bm + ar) * (Kdim) + nk + aq * 4);      \
            pa1 = *(const float4*)((Aptr) + (size_t)(bm + ar + 64) * (Kdim) + nk + aq * 4); \
            pb0 = *(const float4*)((Wptr) + (size_t)(nk + bk) * (Ndim) + bn + bn4);         \
            pb1 = *(const float4*)((Wptr) + (size_t)(nk + bk + 8) * (Ndim) + bn + bn4);     \
        }                                                                       \
        _Pragma("unroll") for (int k = 0; k < TK; ++k) {                        \
            float4 da0 = *(const float4*)&As[buf][k][ty * 4];                   \
            float4 da1 = *(const float4*)&As[buf][k][64 + ty * 4];              \
            float4 db0 = *(const float4*)&Bs[buf][k][tx * 4];                   \
            float4 db1 = *(const float4*)&Bs[buf][k][64 + tx * 4];              \
            const float* dap[2] = {&da0.x, &da1.x};                             \
            const float* dbp[2] = {&db0.x, &db1.x};                             \
            _Pragma("unroll") for (int a = 0; a < 2; ++a)                       \
            _Pragma("unroll") for (int b = 0; b < 2; ++b)                       \
            _Pragma("unroll") for (int i = 0; i < 4; ++i)                       \
            _Pragma("unroll") for (int j = 0; j < 4; ++j)                       \
                acc[a][b][i][j] = fmaf(dap[a][i], dbp[b][j], acc[a][b][i][j]);  \
        }                                                                       \
        if (nk < (Kdim)) {                                                      \
            const int nb = buf ^ 1;                                             \
            STAGE_STORE(nb)                                                     \
            __syncthreads();                                                    \
            buf = nb;                                                           \
        }                                                                       \
    }

// ---------------------------------------------------------------------------
// K1: h1 = relu(F @ Wg1 + b1), fp32.
// ---------------------------------------------------------------------------
__global__ __launch_bounds__(256) void gemm1_f32(
    const float* __restrict__ A, const float* __restrict__ W,
    const float* __restrict__ bias, float* __restrict__ out, int M)
{
    const int K = 1024, N = 256;
    GEMM_MAINLOOP(A, W, K, N)
    #pragma unroll
    for (int a = 0; a < 2; ++a) {
        #pragma unroll
        for (int b = 0; b < 2; ++b) {
            const int col = bn + b * 64 + tx * 4;
            float4 bi = *(const float4*)(bias + col);
            #pragma unroll
            for (int i = 0; i < 4; ++i) {
                const int row = bm + a * 64 + ty * 4 + i;
                float4 o;
                o.x = fmaxf(acc[a][b][i][0] + bi.x, 0.f);
                o.y = fmaxf(acc[a][b][i][1] + bi.y, 0.f);
                o.z = fmaxf(acc[a][b][i][2] + bi.z, 0.f);
                o.w = fmaxf(acc[a][b][i][3] + bi.w, 0.f);
                *(float4*)(out + (size_t)row * N + col) = o;
            }
        }
    }
}

// ---------------------------------------------------------------------------
// K2: z2 = h1 @ Wg2 + b2; g = F * sigmoid(z2); comp = (g>0.3)?0:g.
// fp32 epilogue.  Near-boundary elements -> elist1 for the tiered fp64 fix.
// ---------------------------------------------------------------------------
__global__ __launch_bounds__(256) void gemm2_f32(
    const float* __restrict__ A, const float* __restrict__ W,
    const float* __restrict__ bias, const float* __restrict__ F,
    float* __restrict__ out, unsigned* __restrict__ ectr1,
    uint2* __restrict__ elist1, int M)
{
    const int K = 256, N = 1024;
    GEMM_MAINLOOP(A, W, K, N)
    #pragma unroll
    for (int a = 0; a < 2; ++a) {
        #pragma unroll
        for (int b = 0; b < 2; ++b) {
            const int col = bn + b * 64 + tx * 4;
            float4 bi = *(const float4*)(bias + col);
            const float* bip = &bi.x;
            #pragma unroll
            for (int i = 0; i < 4; ++i) {
                const int row = bm + a * 64 + ty * 4 + i;
                float4 fv = *(const float4*)(F + (size_t)row * N + col);
                const float* fvp = &fv.x;
                float4 o;
                float* op = &o.x;
                #pragma unroll
                for (int j = 0; j < 4; ++j) {
                    float z = acc[a][b][i][j] + bip[j];
                    float gw = 1.0f / (1.0f + __expf(-z));
                    float g = fvp[j] * gw;
                    float c = (g > 0.3f) ? 0.f : g;
                    if (fabsf(g - 0.3f) < B03 || fabsf(fabsf(c) - 0.1f) < B01) {
                        unsigned idx = atomicAdd(ectr1, 1u);
                        if (idx < FIXCAP) elist1[idx] = make_uint2((unsigned)row, (unsigned)(col + j));
                    }
                    op[j] = c;
                }
                *(float4*)(out + (size_t)row * N + col) = o;
            }
        }
    }
}

// ---------------------------------------------------------------------------
// fix_near (tier 1): refine flagged elements with an fp64 dot of the STORED
// fp32 h1 row and the Wg2 column (error vs fp64 ref <= ~2e-6).  Elements
// still within B2 of a boundary escalate to fix_full.  Otherwise write the
// refined value and adjust the per-row sparsity-count correction so the
// count decision matches the fp64 reference exactly.
// ---------------------------------------------------------------------------
__global__ __launch_bounds__(256) void fix_near(
    const float* __restrict__ h1, const float* __restrict__ F,
    const float* __restrict__ Wg2, const float* __restrict__ bg2,
    const unsigned* __restrict__ ectr1, const uint2* __restrict__ elist1,
    unsigned* __restrict__ ectr2, uint2* __restrict__ elist2,
    float* __restrict__ out, int* __restrict__ corr)
{
    __shared__ double red[4];
    const int tid = threadIdx.x;
    unsigned cnt = *ectr1;
    if (cnt > FIXCAP) cnt = FIXCAP;

    for (unsigned e = blockIdx.x; e < cnt; e += gridDim.x) {
        const unsigned row = elist1[e].x, col = elist1[e].y;
        double p = (double)h1[(size_t)row * 256 + tid]
                 * (double)Wg2[(size_t)tid * 1024 + col];
        #pragma unroll
        for (int o = 32; o > 0; o >>= 1) p += __shfl_down(p, o, 64);
        if ((tid & 63) == 0) red[tid >> 6] = p;
        __syncthreads();
        if (tid == 0) {
            double z2 = red[0] + red[1] + red[2] + red[3] + (double)bg2[col];
            double gw = 1.0 / (1.0 + exp(-z2));
            double g = (double)F[(size_t)row * 1024 + col] * gw;
            double c = (g > 0.3) ? 0.0 : g;
            bool near = (fabs(g - 0.3) < B2) || (fabs(fabs(c) - 0.1) < B2);
            if (near) {
                unsigned i2 = atomicAdd(ectr2, 1u);
                if (i2 < FIXCAP) elist2[i2] = make_uint2(row, col);
            } else {
                float cf = (float)c;
                int d_ref = (fabs(c) < 0.1) ? 1 : 0;
                int d_st  = (fabsf(cf) < 0.1f) ? 1 : 0;
                if (d_ref != d_st) atomicAdd(&corr[row], d_ref - d_st);
                out[(size_t)row * 1024 + col] = cf;
            }
        }
        __syncthreads();
    }
}

// ---------------------------------------------------------------------------
// fix_full (tier 2): true fp64 recompute from F (h1 fp64 -> z2 fp64) for the
// few elements too close for tier 1.  Same count-correction mechanism.
// ---------------------------------------------------------------------------
__global__ __launch_bounds__(256) void fix_full(
    const float* __restrict__ F, const float* __restrict__ Wg1,
    const float* __restrict__ bg1, const float* __restrict__ Wg2,
    const float* __restrict__ bg2,
    const unsigned* __restrict__ ectr2, const uint2* __restrict__ elist2,
    float* __restrict__ out, int* __restrict__ corr)
{
    __shared__ float Fs[1024];
    __shared__ double red[4];
    const int tid = threadIdx.x;
    unsigned cnt = *ectr2;
    if (cnt > FIXCAP) cnt = FIXCAP;

    for (unsigned e = blockIdx.x; e < cnt; e += gridDim.x) {
        const unsigned row = elist2[e].x, col = elist2[e].y;
        __syncthreads();
        *(float4*)&Fs[tid * 4] = *(const float4*)(F + (size_t)row * 1024 + tid * 4);
        __syncthreads();
        double pa[8];
        #pragma unroll
        for (int u = 0; u < 8; ++u) pa[u] = 0.0;
        for (int j = 0; j < 1024; j += 8) {
            #pragma unroll
            for (int u = 0; u < 8; ++u)
                pa[u] += (double)Fs[j + u] * (double)Wg1[(size_t)(j + u) * 256 + tid];
        }
        double a = ((pa[0] + pa[1]) + (pa[2] + pa[3])) + ((pa[4] + pa[5]) + (pa[6] + pa[7]));
        double h = a + (double)bg1[tid];
        h = (h > 0.0) ? h : 0.0;
        double p = h * (double)Wg2[(size_t)tid * 1024 + col];
        #pragma unroll
        for (int o = 32; o > 0; o >>= 1) p += __shfl_down(p, o, 64);
        if ((tid & 63) == 0) red[tid >> 6] = p;
        __syncthreads();
        if (tid == 0) {
            double z2 = red[0] + red[1] + red[2] + red[3] + (double)bg2[col];
            double gw = 1.0 / (1.0 + exp(-z2));
            double g = (double)Fs[col] * gw;
            double c = (g > 0.3) ? 0.0 : g;
            float cf = (float)c;
            int d_ref = (fabs(c) < 0.1) ? 1 : 0;
            int d_st  = (fabsf(cf) < 0.1f) ? 1 : 0;
            if (d_ref != d_st) atomicAdd(&corr[row], d_ref - d_st);
            out[(size_t)row * 1024 + col] = cf;
        }
    }
}

// ---------------------------------------------------------------------------
// K3: per-row finalize (in-place on d_out).  One WAVE per row, fp32 fast
// path, sparsity count adjusted by corr[] so cur_sp matches the fp64 ref
// exactly.  Rows with any |dyn| within BDYN of thr skip the store and go to
// row_exact (full fp64 redo from F).
// ---------------------------------------------------------------------------
__global__ __launch_bounds__(256) void finalize_rows(
    float* __restrict__ C,
    const float* __restrict__ wr1, const float* __restrict__ br1,
    const float* __restrict__ wr2, const float* __restrict__ br2,
    const float* __restrict__ wm1, const float* __restrict__ bm1,
    const float* __restrict__ wm2, const float* __restrict__ bm2,
    const int* __restrict__ corr,
    unsigned* __restrict__ rctr, unsigned* __restrict__ rowlist)
{
    const int D = 1024;
    const int tid = threadIdx.x;
    const int lane = tid & 63;
    const unsigned row = blockIdx.x * 4 + (tid >> 6);
    const size_t base = (size_t)row * D;
    const int col0 = lane * 4;

    float4 c4[4];
    #pragma unroll
    for (int q = 0; q < 4; ++q)
        c4[q] = *(const float4*)(C + base + q * 256 + col0);

    float c[16];
    #pragma unroll
    for (int q = 0; q < 4; ++q) {
        c[q * 4 + 0] = c4[q].x; c[q * 4 + 1] = c4[q].y;
        c[q * 4 + 2] = c4[q].z; c[q * 4 + 3] = c4[q].w;
    }

    // current sparsity (integer-exact, ref-matched via corr)
    float cnt = 0.f;
    #pragma unroll
    for (int i = 0; i < 16; ++i) cnt += (fabsf(c[i]) < 0.1f) ? 1.f : 0.f;
    #pragma unroll
    for (int o = 32; o > 0; o >>= 1) cnt += __shfl_xor(cnt, o, 64);
    cnt += (float)corr[row];
    const double cur_sp = (double)cnt / 1024.0;   // exact

    // sparsity_feedback hidden layer (fp64, wave-uniform)
    float hid[16];
    #pragma unroll
    for (int h = 0; h < 16; ++h) {
        double z = cur_sp * (double)wr1[h] + 0.1 * (double)wr1[16 + h] + (double)br1[h];
        hid[h] = (float)((z > 0.0) ? z : 0.0);
    }

    // dyn = comp * sigmoid(hid @ wr2 + br2)  (fp32)
    float dyn[16];
    #pragma unroll
    for (int q = 0; q < 4; ++q) {
        const int cq = q * 256 + col0;
        float4 b4 = *(const float4*)(br2 + cq);
        float z[4] = {b4.x, b4.y, b4.z, b4.w};
        #pragma unroll
        for (int h = 0; h < 16; ++h) {
            float4 w4 = *(const float4*)(wr2 + (size_t)h * D + cq);
            z[0] = fmaf(hid[h], w4.x, z[0]);
            z[1] = fmaf(hid[h], w4.y, z[1]);
            z[2] = fmaf(hid[h], w4.z, z[2]);
            z[3] = fmaf(hid[h], w4.w, z[3]);
        }
        #pragma unroll
        for (int j = 0; j < 4; ++j) {
            float rw = 1.0f / (1.0f + __expf(-z[j]));
            dyn[q * 4 + j] = c[q * 4 + j] * rw;
        }
    }

    // row stats (fp32 butterflies)
    float s = 0.f, mx = -1e30f;
    #pragma unroll
    for (int i = 0; i < 16; ++i) { s += dyn[i]; mx = fmaxf(mx, dyn[i]); }
    #pragma unroll
    for (int o = 32; o > 0; o >>= 1) s += __shfl_xor(s, o, 64);
    const float mean = s / 1024.0f;

    float sq = 0.f;
    #pragma unroll
    for (int i = 0; i < 16; ++i) { float d = dyn[i] - mean; sq = fmaf(d, d, sq); }
    #pragma unroll
    for (int o = 32; o > 0; o >>= 1) sq += __shfl_xor(sq, o, 64);
    const float sd = sqrtf(sq / 1023.0f);

    #pragma unroll
    for (int o = 32; o > 0; o >>= 1) mx = fmaxf(mx, __shfl_xor(mx, o, 64));

    // adaptive threshold (fp64 MLP, wave-uniform)
    double acc2 = (double)bm2[0];
    #pragma unroll
    for (int h = 0; h < 16; ++h) {
        double hz = (double)mean * (double)wm1[h] + (double)sd * (double)wm1[16 + h]
                  + (double)mx * (double)wm1[32 + h] + (double)bm1[h];
        hz = (hz > 0.0) ? hz : 0.0;
        acc2 += hz * (double)wm2[h];
    }
    const float thr = (float)(1.0 / (1.0 + exp(-acc2)));

    bool fl = false;
    #pragma unroll
    for (int i = 0; i < 16; ++i)
        if (fabsf(fabsf(dyn[i]) - thr) < BDYN) fl = true;

    if (__any(fl)) {
        if (lane == 0) {
            unsigned idx = atomicAdd(rctr, 1u);
            if (idx < ROWCAP) rowlist[idx] = row;
        }
        return;                         // preserve comp row for row_exact
    }

    #pragma unroll
    for (int q = 0; q < 4; ++q) {
        float4 o4;
        float* op = &o4.x;
        #pragma unroll
        for (int j = 0; j < 4; ++j) {
            float d = dyn[q * 4 + j];
            op[j] = (fabsf(d) > thr) ? d : 0.f;
        }
        *(float4*)(C + base + q * 256 + col0) = o4;
    }
}

// ---------------------------------------------------------------------------
// fp64 block reduction helper (256 threads).
// ---------------------------------------------------------------------------
__device__ __forceinline__ double block_reduce_d(double v, double* sm, int tid, int op)
{
    #pragma unroll
    for (int o = 32; o > 0; o >>= 1) {
        double other = __shfl_down(v, o, 64);
        v = op ? fmax(v, other) : (v + other);
    }
    if ((tid & 63) == 0) sm[tid >> 6] = v;
    __syncthreads();
    if (tid == 0) {
        double r = sm[0];
        for (int w = 1; w < 4; ++w) r = op ? fmax(r, sm[w]) : (r + sm[w]);
        sm[4] = r;
    }
    __syncthreads();
    double r = sm[4];
    __syncthreads();
    return r;
}

// ---------------------------------------------------------------------------
// row_exact: full fp64 recompute of the ENTIRE pipeline from F for rows near
// the mask boundary (round-3/5-validated math).  Round-6 change is PERF only:
// the h1 dot uses 8 partial accumulators (was a 1024-long serial fp64 chain
// gated on global-load latency -> ~455us/row measured; VALUBusy 4.9%) and the
// z2 loop uses 2-way partials.  fp64 summation-order change ~1e-14, five
// orders below the ~1e-8 decision gaps this kernel resolves.
// ---------------------------------------------------------------------------
__global__ __launch_bounds__(256) void row_exact(
    const float* __restrict__ F,
    const float* __restrict__ wg1, const float* __restrict__ bg1,
    const float* __restrict__ wg2, const float* __restrict__ bg2,
    const float* __restrict__ wr1, const float* __restrict__ br1,
    const float* __restrict__ wr2, const float* __restrict__ br2,
    const float* __restrict__ wm1, const float* __restrict__ bm1,
    const float* __restrict__ wm2, const float* __restrict__ bm2,
    const unsigned* __restrict__ rctr, const unsigned* __restrict__ rowlist,
    float* __restrict__ out)
{
    __shared__ float  Fs[1024];
    __shared__ double h1d[256];
    __shared__ double sm[8];
    const int tid = threadIdx.x;
    unsigned rcnt = *rctr;
    if (rcnt > ROWCAP) rcnt = ROWCAP;

    for (unsigned e = blockIdx.x; e < rcnt; e += gridDim.x) {
        const unsigned row = rowlist[e];
        __syncthreads();
        *(float4*)&Fs[tid * 4] = *(const float4*)(F + (size_t)row * 1024 + tid * 4);
        __syncthreads();

        // h1 (fp64), 8 partial accumulators -> 8 loads in flight, chain/8
        double pa[8];
        #pragma unroll
        for (int u = 0; u < 8; ++u) pa[u] = 0.0;
        for (int j = 0; j < 1024; j += 8) {
            #pragma unroll
            for (int u = 0; u < 8; ++u)
                pa[u] += (double)Fs[j + u] * (double)wg1[(size_t)(j + u) * 256 + tid];
        }
        double a = ((pa[0] + pa[1]) + (pa[2] + pa[3])) + ((pa[4] + pa[5]) + (pa[6] + pa[7]));
        a += (double)bg1[tid];
        h1d[tid] = (a > 0.0) ? a : 0.0;
        __syncthreads();

        // z2 (fp64), 2-way partials x unroll 4 -> 8 float4 loads in flight
        const int c0 = tid * 4;
        double zA[4] = {0.0, 0.0, 0.0, 0.0};
        double zB[4] = {0.0, 0.0, 0.0, 0.0};
        #pragma unroll 4
        for (int j = 0; j < 256; j += 2) {
            float4 wA = *(const float4*)(wg2 + (size_t)j * 1024 + c0);
            float4 wB = *(const float4*)(wg2 + (size_t)(j + 1) * 1024 + c0);
            double hA = h1d[j], hB = h1d[j + 1];
            zA[0] += hA * (double)wA.x; zA[1] += hA * (double)wA.y;
            zA[2] += hA * (double)wA.z; zA[3] += hA * (double)wA.w;
            zB[0] += hB * (double)wB.x; zB[1] += hB * (double)wB.y;
            zB[2] += hB * (double)wB.z; zB[3] += hB * (double)wB.w;
        }
        double comp[4];
        double cnt = 0.0;
        #pragma unroll
        for (int j = 0; j < 4; ++j) {
            double z2v = (double)bg2[c0 + j] + zA[j] + zB[j];
            double gw = 1.0 / (1.0 + exp(-z2v));
            double g = (double)Fs[c0 + j] * gw;
            double cm = (g > 0.3) ? 0.0 : g;
            comp[j] = cm;
            cnt += (fabs(cm) < 0.1) ? 1.0 : 0.0;
        }
        cnt = block_reduce_d(cnt, sm, tid, 0);
        const double cur_sp = cnt / 1024.0;

        double hid[16];
        #pragma unroll
        for (int h = 0; h < 16; ++h) {
            double hz = cur_sp * (double)wr1[h] + 0.1 * (double)wr1[16 + h] + (double)br1[h];
            hid[h] = (hz > 0.0) ? hz : 0.0;
        }
        double zr[4] = {(double)br2[c0], (double)br2[c0 + 1],
                        (double)br2[c0 + 2], (double)br2[c0 + 3]};
        #pragma unroll
        for (int h = 0; h < 16; ++h) {
            float4 w4 = *(const float4*)(wr2 + (size_t)h * 1024 + c0);
            zr[0] += hid[h] * (double)w4.x; zr[1] += hid[h] * (double)w4.y;
            zr[2] += hid[h] * (double)w4.z; zr[3] += hid[h] * (double)w4.w;
        }
        double dyn[4];
        #pragma unroll
        for (int j = 0; j < 4; ++j) {
            double rw = 1.0 / (1.0 + exp(-zr[j]));
            dyn[j] = comp[j] * rw;
        }

        double s = dyn[0] + dyn[1] + dyn[2] + dyn[3];
        s = block_reduce_d(s, sm, tid, 0);
        const double mean = s / 1024.0;

        double sq = 0.0;
        #pragma unroll
        for (int j = 0; j < 4; ++j) { double d = dyn[j] - mean; sq += d * d; }
        sq = block_reduce_d(sq, sm, tid, 0);
        const double sd = sqrt(sq / 1023.0);

        double mx = fmax(fmax(dyn[0], dyn[1]), fmax(dyn[2], dyn[3]));
        mx = block_reduce_d(mx, sm, tid, 1);

        double acc2 = (double)bm2[0];
        #pragma unroll
        for (int h = 0; h < 16; ++h) {
            double hz = mean * (double)wm1[h] + sd * (double)wm1[16 + h]
                      + mx * (double)wm1[32 + h] + (double)bm1[h];
            hz = (hz > 0.0) ? hz : 0.0;
            acc2 += hz * (double)wm2[h];
        }
        const double thr = 1.0 / (1.0 + exp(-acc2));

        float4 o4;
        o4.x = (float)((fabs(dyn[0]) > thr) ? dyn[0] : 0.0);
        o4.y = (float)((fabs(dyn[1]) > thr) ? dyn[1] : 0.0);
        o4.z = (float)((fabs(dyn[2]) > thr) ? dyn[2] : 0.0);
        o4.w = (float)((fabs(dyn[3]) > thr) ? dyn[3] : 0.0);
        *(float4*)(out + (size_t)row * 1024 + c0) = o4;
    }
}

// ---------------------------------------------------------------------------
extern "C" void kernel_launch(void* const* d_in, const int* in_sizes, int n_in,
                              void* d_out, int out_size, void* d_ws, size_t ws_size,
                              hipStream_t stream)
{
    const float* F   = (const float*)d_in[0];
    const float* wg1 = (const float*)d_in[1];
    const float* bg1 = (const float*)d_in[2];
    const float* wg2 = (const float*)d_in[3];
    const float* bg2 = (const float*)d_in[4];
    // d_in[5..8]: competition calculator — provably dead (win == False always)
    const float* wr1 = (const float*)d_in[9];
    const float* br1 = (const float*)d_in[10];
    const float* wr2 = (const float*)d_in[11];
    const float* br2 = (const float*)d_in[12];
    const float* wm1 = (const float*)d_in[13];
    const float* bm1 = (const float*)d_in[14];
    const float* wm2 = (const float*)d_in[15];
    const float* bm2 = (const float*)d_in[16];

    float* out = (float*)d_out;
    const int M = in_sizes[0] / 1024;                      // 32768

    char* ws = (char*)d_ws;
    float*    h1      = (float*)ws;                              // 32 MiB
    uint2*    elist1  = (uint2*)(ws + (32u << 20));              // 2 MiB
    uint2*    elist2  = (uint2*)(ws + (34u << 20));              // 2 MiB
    unsigned* rowlist = (unsigned*)(ws + (36u << 20));           // 128 KiB
    int*      corr    = (int*)(ws + (36u << 20) + (128u << 10)); // 128 KiB
    unsigned* ctrs    = (unsigned*)(ws + (36u << 20) + (256u << 10));
    unsigned* ectr1 = ctrs, *ectr2 = ctrs + 1, *rctr = ctrs + 2;

    // zero corr + counters in one shot (contiguous)
    hipMemsetAsync(corr, 0, (size_t)M * sizeof(int) + 16, stream);
    gemm1_f32<<<dim3(M / TM, 256 / TN), 256, 0, stream>>>(F, wg1, bg1, h1, M);
    gemm2_f32<<<dim3(M / TM, 1024 / TN), 256, 0, stream>>>(h1, wg2, bg2, F, out, ectr1, elist1, M);
    fix_near<<<2048, 256, 0, stream>>>(h1, F, wg2, bg2, ectr1, elist1, ectr2, elist2, out, corr);
    fix_full<<<1024, 256, 0, stream>>>(F, wg1, bg1, wg2, bg2, ectr2, elist2, out, corr);
    finalize_rows<<<M / 4, 256, 0, stream>>>(out, wr1, br1, wr2, br2, wm1, bm1, wm2, bm2,
                                             corr, rctr, rowlist);
    row_exact<<<2048, 256, 0, stream>>>(F, wg1, bg1, wg2, bg2, wr1, br1, wr2, br2,
                                        wm1, bm1, wm2, bm2, rctr, rowlist, out);
}

// Round 7
// 1135.917 us; speedup vs baseline: 1.5353x; 1.0654x over previous
//
#include <hip/hip_runtime.h>
#include <cmath>

#define TM 128
#define TN 128
#define TK 16
#define LDSW 132          // padded LDS row width (floats)
#define FIXCAP 262144u
#define ROWCAP 32768u

// Decision-boundary protection bands (UNCHANGED from validated rounds 5/6).
#define B03  2.5e-5f      // g vs 0.3            -> element fix (tier 1)
#define B01  2.5e-5f      // |comp| vs 0.1       -> element fix (tier 1)
#define B2   5e-6         // tier-1 residual band -> tier-2 full fp64 fix
#define BDYN 3e-5f        // |dyn| vs thr        -> row fp64 redo (row_exact)

// ---------------------------------------------------------------------------
// Shared 128x128x16 fp32 tile mainloop (validated rounds 2/3/5/6).
// ---------------------------------------------------------------------------
#define STAGE_STORE(B)                                                          \
        As[B][aq * 4 + 0][ar] = pa0.x; As[B][aq * 4 + 1][ar] = pa0.y;           \
        As[B][aq * 4 + 2][ar] = pa0.z; As[B][aq * 4 + 3][ar] = pa0.w;           \
        As[B][aq * 4 + 0][ar + 64] = pa1.x; As[B][aq * 4 + 1][ar + 64] = pa1.y; \
        As[B][aq * 4 + 2][ar + 64] = pa1.z; As[B][aq * 4 + 3][ar + 64] = pa1.w; \
        *(float4*)&Bs[B][bk][bn4] = pb0;                                        \
        *(float4*)&Bs[B][bk + 8][bn4] = pb1;

#define GEMM_MAINLOOP(Aptr, Wptr, Kdim, Ndim)                                   \
    __shared__ float As[2][TK][LDSW];                                           \
    __shared__ float Bs[2][TK][LDSW];                                           \
    const int tid = threadIdx.x;                                                \
    const int bm = blockIdx.x * TM;                                             \
    const int bn = blockIdx.y * TN;                                             \
    const int tx = tid & 15, ty = tid >> 4;                                     \
    const int ar = tid >> 2, aq = tid & 3;                                      \
    const int bk = tid >> 5, bn4 = (tid & 31) * 4;                              \
    float acc[2][2][4][4];                                                      \
    _Pragma("unroll") for (int a = 0; a < 2; ++a)                               \
    _Pragma("unroll") for (int b = 0; b < 2; ++b)                               \
    _Pragma("unroll") for (int i = 0; i < 4; ++i)                               \
    _Pragma("unroll") for (int j = 0; j < 4; ++j) acc[a][b][i][j] = 0.f;        \
    float4 pa0 = *(const float4*)((Aptr) + (size_t)(bm + ar) * (Kdim) + aq * 4);      \
    float4 pa1 = *(const float4*)((Aptr) + (size_t)(bm + ar + 64) * (Kdim) + aq * 4); \
    float4 pb0 = *(const float4*)((Wptr) + (size_t)bk * (Ndim) + bn + bn4);           \
    float4 pb1 = *(const float4*)((Wptr) + (size_t)(bk + 8) * (Ndim) + bn + bn4);     \
    STAGE_STORE(0)                                                              \
    __syncthreads();                                                            \
    int buf = 0;                                                                \
    for (int k0 = 0; k0 < (Kdim); k0 += TK) {                                   \
        const int nk = k0 + TK;                                                 \
        if (nk < (Kdim)) {                                                      \
            pa0 = *(const float4*)((Aptr) + (size_t)(bm + ar) * (Kdim) + nk + aq * 4);      \
            pa1 = *(const float4*)((Aptr) + (size_t)(bm + ar + 64) * (Kdim) + nk + aq * 4); \
            pb0 = *(const float4*)((Wptr) + (size_t)(nk + bk) * (Ndim) + bn + bn4);         \
            pb1 = *(const float4*)((Wptr) + (size_t)(nk + bk + 8) * (Ndim) + bn + bn4);     \
        }                                                                       \
        _Pragma("unroll") for (int k = 0; k < TK; ++k) {                        \
            float4 da0 = *(const float4*)&As[buf][k][ty * 4];                   \
            float4 da1 = *(const float4*)&As[buf][k][64 + ty * 4];              \
            float4 db0 = *(const float4*)&Bs[buf][k][tx * 4];                   \
            float4 db1 = *(const float4*)&Bs[buf][k][64 + tx * 4];              \
            const float* dap[2] = {&da0.x, &da1.x};                             \
            const float* dbp[2] = {&db0.x, &db1.x};                             \
            _Pragma("unroll") for (int a = 0; a < 2; ++a)                       \
            _Pragma("unroll") for (int b = 0; b < 2; ++b)                       \
            _Pragma("unroll") for (int i = 0; i < 4; ++i)                       \
            _Pragma("unroll") for (int j = 0; j < 4; ++j)                       \
                acc[a][b][i][j] = fmaf(dap[a][i], dbp[b][j], acc[a][b][i][j]);  \
        }                                                                       \
        if (nk < (Kdim)) {                                                      \
            const int nb = buf ^ 1;                                             \
            STAGE_STORE(nb)                                                     \
            __syncthreads();                                                    \
            buf = nb;                                                           \
        }                                                                       \
    }

// ---------------------------------------------------------------------------
// K1: h1 = relu(F @ Wg1 + b1), fp32.
// ---------------------------------------------------------------------------
__global__ __launch_bounds__(256) void gemm1_f32(
    const float* __restrict__ A, const float* __restrict__ W,
    const float* __restrict__ bias, float* __restrict__ out, int M)
{
    const int K = 1024, N = 256;
    GEMM_MAINLOOP(A, W, K, N)
    #pragma unroll
    for (int a = 0; a < 2; ++a) {
        #pragma unroll
        for (int b = 0; b < 2; ++b) {
            const int col = bn + b * 64 + tx * 4;
            float4 bi = *(const float4*)(bias + col);
            #pragma unroll
            for (int i = 0; i < 4; ++i) {
                const int row = bm + a * 64 + ty * 4 + i;
                float4 o;
                o.x = fmaxf(acc[a][b][i][0] + bi.x, 0.f);
                o.y = fmaxf(acc[a][b][i][1] + bi.y, 0.f);
                o.z = fmaxf(acc[a][b][i][2] + bi.z, 0.f);
                o.w = fmaxf(acc[a][b][i][3] + bi.w, 0.f);
                *(float4*)(out + (size_t)row * N + col) = o;
            }
        }
    }
}

// ---------------------------------------------------------------------------
// K2: z2 = h1 @ Wg2 + b2; g = F * sigmoid(z2); comp = (g>0.3)?0:g.
// fp32 epilogue.  Near-boundary elements -> elist1 for the tiered fp64 fix.
// ---------------------------------------------------------------------------
__global__ __launch_bounds__(256) void gemm2_f32(
    const float* __restrict__ A, const float* __restrict__ W,
    const float* __restrict__ bias, const float* __restrict__ F,
    float* __restrict__ out, unsigned* __restrict__ ectr1,
    uint2* __restrict__ elist1, int M)
{
    const int K = 256, N = 1024;
    GEMM_MAINLOOP(A, W, K, N)
    #pragma unroll
    for (int a = 0; a < 2; ++a) {
        #pragma unroll
        for (int b = 0; b < 2; ++b) {
            const int col = bn + b * 64 + tx * 4;
            float4 bi = *(const float4*)(bias + col);
            const float* bip = &bi.x;
            #pragma unroll
            for (int i = 0; i < 4; ++i) {
                const int row = bm + a * 64 + ty * 4 + i;
                float4 fv = *(const float4*)(F + (size_t)row * N + col);
                const float* fvp = &fv.x;
                float4 o;
                float* op = &o.x;
                #pragma unroll
                for (int j = 0; j < 4; ++j) {
                    float z = acc[a][b][i][j] + bip[j];
                    float gw = 1.0f / (1.0f + __expf(-z));
                    float g = fvp[j] * gw;
                    float c = (g > 0.3f) ? 0.f : g;
                    if (fabsf(g - 0.3f) < B03 || fabsf(fabsf(c) - 0.1f) < B01) {
                        unsigned idx = atomicAdd(ectr1, 1u);
                        if (idx < FIXCAP) elist1[idx] = make_uint2((unsigned)row, (unsigned)(col + j));
                    }
                    op[j] = c;
                }
                *(float4*)(out + (size_t)row * N + col) = o;
            }
        }
    }
}

// ---------------------------------------------------------------------------
// fix_near (tier 1): refine flagged elements with an fp64 dot of the STORED
// fp32 h1 row and the Wg2 column.  Escalate still-near elements to fix_full.
// ---------------------------------------------------------------------------
__global__ __launch_bounds__(256) void fix_near(
    const float* __restrict__ h1, const float* __restrict__ F,
    const float* __restrict__ Wg2, const float* __restrict__ bg2,
    const unsigned* __restrict__ ectr1, const uint2* __restrict__ elist1,
    unsigned* __restrict__ ectr2, uint2* __restrict__ elist2,
    float* __restrict__ out, int* __restrict__ corr)
{
    __shared__ double red[4];
    const int tid = threadIdx.x;
    unsigned cnt = *ectr1;
    if (cnt > FIXCAP) cnt = FIXCAP;

    for (unsigned e = blockIdx.x; e < cnt; e += gridDim.x) {
        const unsigned row = elist1[e].x, col = elist1[e].y;
        double p = (double)h1[(size_t)row * 256 + tid]
                 * (double)Wg2[(size_t)tid * 1024 + col];
        #pragma unroll
        for (int o = 32; o > 0; o >>= 1) p += __shfl_down(p, o, 64);
        if ((tid & 63) == 0) red[tid >> 6] = p;
        __syncthreads();
        if (tid == 0) {
            double z2 = red[0] + red[1] + red[2] + red[3] + (double)bg2[col];
            double gw = 1.0 / (1.0 + exp(-z2));
            double g = (double)F[(size_t)row * 1024 + col] * gw;
            double c = (g > 0.3) ? 0.0 : g;
            bool near = (fabs(g - 0.3) < B2) || (fabs(fabs(c) - 0.1) < B2);
            if (near) {
                unsigned i2 = atomicAdd(ectr2, 1u);
                if (i2 < FIXCAP) elist2[i2] = make_uint2(row, col);
            } else {
                float cf = (float)c;
                int d_ref = (fabs(c) < 0.1) ? 1 : 0;
                int d_st  = (fabsf(cf) < 0.1f) ? 1 : 0;
                if (d_ref != d_st) atomicAdd(&corr[row], d_ref - d_st);
                out[(size_t)row * 1024 + col] = cf;
            }
        }
        __syncthreads();
    }
}

// ---------------------------------------------------------------------------
// fix_full (tier 2): true fp64 recompute from F.  ROUND-7 perf restructure:
// wg1 read via cooperative LDS tile staging (32 k-rows = 32 KB contiguous,
// 8 coalesced float4 loads/thread) instead of a per-thread latency chain of
// 1024 strided loads.  fp64 math identical; summation-order delta ~1e-14.
// ---------------------------------------------------------------------------
__global__ __launch_bounds__(256) void fix_full(
    const float* __restrict__ F, const float* __restrict__ Wg1,
    const float* __restrict__ bg1, const float* __restrict__ Wg2,
    const float* __restrict__ bg2,
    const unsigned* __restrict__ ectr2, const uint2* __restrict__ elist2,
    float* __restrict__ out, int* __restrict__ corr)
{
    __shared__ float Fs[1024];
    __shared__ float WtF[8192];     // 32 KB weight tile
    __shared__ double red[4];
    const int tid = threadIdx.x;
    unsigned cnt = *ectr2;
    if (cnt > FIXCAP) cnt = FIXCAP;

    for (unsigned e = blockIdx.x; e < cnt; e += gridDim.x) {
        const unsigned row = elist2[e].x, col = elist2[e].y;
        __syncthreads();
        *(float4*)&Fs[tid * 4] = *(const float4*)(F + (size_t)row * 1024 + tid * 4);
        double pa = 0.0, pb = 0.0;
        for (int k0 = 0; k0 < 1024; k0 += 32) {
            __syncthreads();
            #pragma unroll
            for (int r = 0; r < 8; ++r)
                *(float4*)&WtF[r * 1024 + tid * 4] =
                    *(const float4*)(Wg1 + (size_t)k0 * 256 + r * 1024 + tid * 4);
            __syncthreads();
            #pragma unroll
            for (int kk = 0; kk < 32; kk += 2) {
                pa += (double)Fs[k0 + kk]     * (double)WtF[kk * 256 + tid];
                pb += (double)Fs[k0 + kk + 1] * (double)WtF[(kk + 1) * 256 + tid];
            }
        }
        double h = (pa + pb) + (double)bg1[tid];
        h = (h > 0.0) ? h : 0.0;
        double p = h * (double)Wg2[(size_t)tid * 1024 + col];
        #pragma unroll
        for (int o = 32; o > 0; o >>= 1) p += __shfl_down(p, o, 64);
        if ((tid & 63) == 0) red[tid >> 6] = p;
        __syncthreads();
        if (tid == 0) {
            double z2 = red[0] + red[1] + red[2] + red[3] + (double)bg2[col];
            double gw = 1.0 / (1.0 + exp(-z2));
            double g = (double)Fs[col] * gw;
            double c = (g > 0.3) ? 0.0 : g;
            float cf = (float)c;
            int d_ref = (fabs(c) < 0.1) ? 1 : 0;
            int d_st  = (fabsf(cf) < 0.1f) ? 1 : 0;
            if (d_ref != d_st) atomicAdd(&corr[row], d_ref - d_st);
            out[(size_t)row * 1024 + col] = cf;
        }
    }
}

// ---------------------------------------------------------------------------
// K3: per-row finalize (unchanged, validated rounds 5/6).
// ---------------------------------------------------------------------------
__global__ __launch_bounds__(256) void finalize_rows(
    float* __restrict__ C,
    const float* __restrict__ wr1, const float* __restrict__ br1,
    const float* __restrict__ wr2, const float* __restrict__ br2,
    const float* __restrict__ wm1, const float* __restrict__ bm1,
    const float* __restrict__ wm2, const float* __restrict__ bm2,
    const int* __restrict__ corr,
    unsigned* __restrict__ rctr, unsigned* __restrict__ rowlist)
{
    const int D = 1024;
    const int tid = threadIdx.x;
    const int lane = tid & 63;
    const unsigned row = blockIdx.x * 4 + (tid >> 6);
    const size_t base = (size_t)row * D;
    const int col0 = lane * 4;

    float4 c4[4];
    #pragma unroll
    for (int q = 0; q < 4; ++q)
        c4[q] = *(const float4*)(C + base + q * 256 + col0);

    float c[16];
    #pragma unroll
    for (int q = 0; q < 4; ++q) {
        c[q * 4 + 0] = c4[q].x; c[q * 4 + 1] = c4[q].y;
        c[q * 4 + 2] = c4[q].z; c[q * 4 + 3] = c4[q].w;
    }

    float cnt = 0.f;
    #pragma unroll
    for (int i = 0; i < 16; ++i) cnt += (fabsf(c[i]) < 0.1f) ? 1.f : 0.f;
    #pragma unroll
    for (int o = 32; o > 0; o >>= 1) cnt += __shfl_xor(cnt, o, 64);
    cnt += (float)corr[row];
    const double cur_sp = (double)cnt / 1024.0;

    float hid[16];
    #pragma unroll
    for (int h = 0; h < 16; ++h) {
        double z = cur_sp * (double)wr1[h] + 0.1 * (double)wr1[16 + h] + (double)br1[h];
        hid[h] = (float)((z > 0.0) ? z : 0.0);
    }

    float dyn[16];
    #pragma unroll
    for (int q = 0; q < 4; ++q) {
        const int cq = q * 256 + col0;
        float4 b4 = *(const float4*)(br2 + cq);
        float z[4] = {b4.x, b4.y, b4.z, b4.w};
        #pragma unroll
        for (int h = 0; h < 16; ++h) {
            float4 w4 = *(const float4*)(wr2 + (size_t)h * D + cq);
            z[0] = fmaf(hid[h], w4.x, z[0]);
            z[1] = fmaf(hid[h], w4.y, z[1]);
            z[2] = fmaf(hid[h], w4.z, z[2]);
            z[3] = fmaf(hid[h], w4.w, z[3]);
        }
        #pragma unroll
        for (int j = 0; j < 4; ++j) {
            float rw = 1.0f / (1.0f + __expf(-z[j]));
            dyn[q * 4 + j] = c[q * 4 + j] * rw;
        }
    }

    float s = 0.f, mx = -1e30f;
    #pragma unroll
    for (int i = 0; i < 16; ++i) { s += dyn[i]; mx = fmaxf(mx, dyn[i]); }
    #pragma unroll
    for (int o = 32; o > 0; o >>= 1) s += __shfl_xor(s, o, 64);
    const float mean = s / 1024.0f;

    float sq = 0.f;
    #pragma unroll
    for (int i = 0; i < 16; ++i) { float d = dyn[i] - mean; sq = fmaf(d, d, sq); }
    #pragma unroll
    for (int o = 32; o > 0; o >>= 1) sq += __shfl_xor(sq, o, 64);
    const float sd = sqrtf(sq / 1023.0f);

    #pragma unroll
    for (int o = 32; o > 0; o >>= 1) mx = fmaxf(mx, __shfl_xor(mx, o, 64));

    double acc2 = (double)bm2[0];
    #pragma unroll
    for (int h = 0; h < 16; ++h) {
        double hz = (double)mean * (double)wm1[h] + (double)sd * (double)wm1[16 + h]
                  + (double)mx * (double)wm1[32 + h] + (double)bm1[h];
        hz = (hz > 0.0) ? hz : 0.0;
        acc2 += hz * (double)wm2[h];
    }
    const float thr = (float)(1.0 / (1.0 + exp(-acc2)));

    bool fl = false;
    #pragma unroll
    for (int i = 0; i < 16; ++i)
        if (fabsf(fabsf(dyn[i]) - thr) < BDYN) fl = true;

    if (__any(fl)) {
        if (lane == 0) {
            unsigned idx = atomicAdd(rctr, 1u);
            if (idx < ROWCAP) rowlist[idx] = row;
        }
        return;                         // preserve comp row for row_exact
    }

    #pragma unroll
    for (int q = 0; q < 4; ++q) {
        float4 o4;
        float* op = &o4.x;
        #pragma unroll
        for (int j = 0; j < 4; ++j) {
            float d = dyn[q * 4 + j];
            op[j] = (fabsf(d) > thr) ? d : 0.f;
        }
        *(float4*)(C + base + q * 256 + col0) = o4;
    }
}

// ---------------------------------------------------------------------------
// fp64 block reduction helper (256 threads).
// ---------------------------------------------------------------------------
__device__ __forceinline__ double block_reduce_d(double v, double* sm, int tid, int op)
{
    #pragma unroll
    for (int o = 32; o > 0; o >>= 1) {
        double other = __shfl_down(v, o, 64);
        v = op ? fmax(v, other) : (v + other);
    }
    if ((tid & 63) == 0) sm[tid >> 6] = v;
    __syncthreads();
    if (tid == 0) {
        double r = sm[0];
        for (int w = 1; w < 4; ++w) r = op ? fmax(r, sm[w]) : (r + sm[w]);
        sm[4] = r;
    }
    __syncthreads();
    double r = sm[4];
    __syncthreads();
    return r;
}

// ---------------------------------------------------------------------------
// row_exact: full fp64 recompute of the ENTIRE pipeline from F for rows near
// the mask boundary (round-3/5/6-validated math).  ROUND-7 perf restructure:
// both weight streams staged through LDS as contiguous 32 KB tiles with
// coalesced cooperative loads (wg1: 32 k-rows; wg2: 8 k-rows), replacing the
// per-thread strided latency chains (413us/row measured, VALUBusy 5%).
// fp64 math identical; summation-order delta ~1e-14.
// ---------------------------------------------------------------------------
__global__ __launch_bounds__(256) void row_exact(
    const float* __restrict__ F,
    const float* __restrict__ wg1, const float* __restrict__ bg1,
    const float* __restrict__ wg2, const float* __restrict__ bg2,
    const float* __restrict__ wr1, const float* __restrict__ br1,
    const float* __restrict__ wr2, const float* __restrict__ br2,
    const float* __restrict__ wm1, const float* __restrict__ bm1,
    const float* __restrict__ wm2, const float* __restrict__ bm2,
    const unsigned* __restrict__ rctr, const unsigned* __restrict__ rowlist,
    float* __restrict__ out)
{
    __shared__ float  Fs[1024];
    __shared__ float  WtF[8192];    // 32 KB weight tile (shared by both phases)
    __shared__ double h1d[256];
    __shared__ double sm[8];
    const int tid = threadIdx.x;
    unsigned rcnt = *rctr;
    if (rcnt > ROWCAP) rcnt = ROWCAP;

    for (unsigned e = blockIdx.x; e < rcnt; e += gridDim.x) {
        const unsigned row = rowlist[e];
        __syncthreads();
        *(float4*)&Fs[tid * 4] = *(const float4*)(F + (size_t)row * 1024 + tid * 4);

        // ---- h1 (fp64): 32-k LDS-staged tiles of wg1 ----
        double pa = 0.0, pb = 0.0;
        for (int k0 = 0; k0 < 1024; k0 += 32) {
            __syncthreads();
            #pragma unroll
            for (int r = 0; r < 8; ++r)
                *(float4*)&WtF[r * 1024 + tid * 4] =
                    *(const float4*)(wg1 + (size_t)k0 * 256 + r * 1024 + tid * 4);
            __syncthreads();
            #pragma unroll
            for (int kk = 0; kk < 32; kk += 2) {
                pa += (double)Fs[k0 + kk]     * (double)WtF[kk * 256 + tid];
                pb += (double)Fs[k0 + kk + 1] * (double)WtF[(kk + 1) * 256 + tid];
            }
        }
        double a = (pa + pb) + (double)bg1[tid];
        h1d[tid] = (a > 0.0) ? a : 0.0;

        // ---- z2 (fp64): 8-k LDS-staged tiles of wg2 ----
        const int c0 = tid * 4;
        double zA[4] = {0.0, 0.0, 0.0, 0.0};
        double zB[4] = {0.0, 0.0, 0.0, 0.0};
        for (int j0 = 0; j0 < 256; j0 += 8) {
            __syncthreads();
            #pragma unroll
            for (int r = 0; r < 8; ++r)
                *(float4*)&WtF[r * 1024 + tid * 4] =
                    *(const float4*)(wg2 + (size_t)j0 * 1024 + r * 1024 + tid * 4);
            __syncthreads();
            #pragma unroll
            for (int kk = 0; kk < 8; kk += 2) {
                float4 wA = *(const float4*)&WtF[kk * 1024 + c0];
                float4 wB = *(const float4*)&WtF[(kk + 1) * 1024 + c0];
                double hA = h1d[j0 + kk], hB = h1d[j0 + kk + 1];
                zA[0] += hA * (double)wA.x; zA[1] += hA * (double)wA.y;
                zA[2] += hA * (double)wA.z; zA[3] += hA * (double)wA.w;
                zB[0] += hB * (double)wB.x; zB[1] += hB * (double)wB.y;
                zB[2] += hB * (double)wB.z; zB[3] += hB * (double)wB.w;
            }
        }
        double comp[4];
        double cnt = 0.0;
        #pragma unroll
        for (int j = 0; j < 4; ++j) {
            double z2v = (double)bg2[c0 + j] + zA[j] + zB[j];
            double gw = 1.0 / (1.0 + exp(-z2v));
            double g = (double)Fs[c0 + j] * gw;
            double cm = (g > 0.3) ? 0.0 : g;
            comp[j] = cm;
            cnt += (fabs(cm) < 0.1) ? 1.0 : 0.0;
        }
        cnt = block_reduce_d(cnt, sm, tid, 0);
        const double cur_sp = cnt / 1024.0;

        double hid[16];
        #pragma unroll
        for (int h = 0; h < 16; ++h) {
            double hz = cur_sp * (double)wr1[h] + 0.1 * (double)wr1[16 + h] + (double)br1[h];
            hid[h] = (hz > 0.0) ? hz : 0.0;
        }
        double zr[4] = {(double)br2[c0], (double)br2[c0 + 1],
                        (double)br2[c0 + 2], (double)br2[c0 + 3]};
        #pragma unroll
        for (int h = 0; h < 16; ++h) {
            float4 w4 = *(const float4*)(wr2 + (size_t)h * 1024 + c0);
            zr[0] += hid[h] * (double)w4.x; zr[1] += hid[h] * (double)w4.y;
            zr[2] += hid[h] * (double)w4.z; zr[3] += hid[h] * (double)w4.w;
        }
        double dyn[4];
        #pragma unroll
        for (int j = 0; j < 4; ++j) {
            double rw = 1.0 / (1.0 + exp(-zr[j]));
            dyn[j] = comp[j] * rw;
        }

        double s = dyn[0] + dyn[1] + dyn[2] + dyn[3];
        s = block_reduce_d(s, sm, tid, 0);
        const double mean = s / 1024.0;

        double sq = 0.0;
        #pragma unroll
        for (int j = 0; j < 4; ++j) { double d = dyn[j] - mean; sq += d * d; }
        sq = block_reduce_d(sq, sm, tid, 0);
        const double sd = sqrt(sq / 1023.0);

        double mx = fmax(fmax(dyn[0], dyn[1]), fmax(dyn[2], dyn[3]));
        mx = block_reduce_d(mx, sm, tid, 1);

        double acc2 = (double)bm2[0];
        #pragma unroll
        for (int h = 0; h < 16; ++h) {
            double hz = mean * (double)wm1[h] + sd * (double)wm1[16 + h]
                      + mx * (double)wm1[32 + h] + (double)bm1[h];
            hz = (hz > 0.0) ? hz : 0.0;
            acc2 += hz * (double)wm2[h];
        }
        const double thr = 1.0 / (1.0 + exp(-acc2));

        float4 o4;
        o4.x = (float)((fabs(dyn[0]) > thr) ? dyn[0] : 0.0);
        o4.y = (float)((fabs(dyn[1]) > thr) ? dyn[1] : 0.0);
        o4.z = (float)((fabs(dyn[2]) > thr) ? dyn[2] : 0.0);
        o4.w = (float)((fabs(dyn[3]) > thr) ? dyn[3] : 0.0);
        *(float4*)(out + (size_t)row * 1024 + c0) = o4;
    }
}

// ---------------------------------------------------------------------------
extern "C" void kernel_launch(void* const* d_in, const int* in_sizes, int n_in,
                              void* d_out, int out_size, void* d_ws, size_t ws_size,
                              hipStream_t stream)
{
    const float* F   = (const float*)d_in[0];
    const float* wg1 = (const float*)d_in[1];
    const float* bg1 = (const float*)d_in[2];
    const float* wg2 = (const float*)d_in[3];
    const float* bg2 = (const float*)d_in[4];
    // d_in[5..8]: competition calculator — provably dead (win == False always)
    const float* wr1 = (const float*)d_in[9];
    const float* br1 = (const float*)d_in[10];
    const float* wr2 = (const float*)d_in[11];
    const float* br2 = (const float*)d_in[12];
    const float* wm1 = (const float*)d_in[13];
    const float* bm1 = (const float*)d_in[14];
    const float* wm2 = (const float*)d_in[15];
    const float* bm2 = (const float*)d_in[16];

    float* out = (float*)d_out;
    const int M = in_sizes[0] / 1024;                      // 32768

    char* ws = (char*)d_ws;
    float*    h1      = (float*)ws;                              // 32 MiB
    uint2*    elist1  = (uint2*)(ws + (32u << 20));              // 2 MiB
    uint2*    elist2  = (uint2*)(ws + (34u << 20));              // 2 MiB
    unsigned* rowlist = (unsigned*)(ws + (36u << 20));           // 128 KiB
    int*      corr    = (int*)(ws + (36u << 20) + (128u << 10)); // 128 KiB
    unsigned* ctrs    = (unsigned*)(ws + (36u << 20) + (256u << 10));
    unsigned* ectr1 = ctrs, *ectr2 = ctrs + 1, *rctr = ctrs + 2;

    // zero corr + counters in one shot (contiguous)
    hipMemsetAsync(corr, 0, (size_t)M * sizeof(int) + 16, stream);
    gemm1_f32<<<dim3(M / TM, 256 / TN), 256, 0, stream>>>(F, wg1, bg1, h1, M);
    gemm2_f32<<<dim3(M / TM, 1024 / TN), 256, 0, stream>>>(h1, wg2, bg2, F, out, ectr1, elist1, M);
    fix_near<<<2048, 256, 0, stream>>>(h1, F, wg2, bg2, ectr1, elist1, ectr2, elist2, out, corr);
    fix_full<<<1024, 256, 0, stream>>>(F, wg1, bg1, wg2, bg2, ectr2, elist2, out, corr);
    finalize_rows<<<M / 4, 256, 0, stream>>>(out, wr1, br1, wr2, br2, wm1, bm1, wm2, bm2,
                                             corr, rctr, rowlist);
    row_exact<<<2048, 256, 0, stream>>>(F, wg1, bg1, wg2, bg2, wr1, br1, wr2, br2,
                                        wm1, bm1, wm2, bm2, rctr, rowlist, out);
}

// Round 8
// 960.622 us; speedup vs baseline: 1.8155x; 1.1825x over previous
//
#include <hip/hip_runtime.h>
#include <cmath>

#define TM 128
#define TN 128
#define TK 16
#define LDSW 132          // padded LDS row width (floats)
#define FIXCAP 262144u
#define ROWCAP 32768u

// Decision-boundary protection bands (UNCHANGED from validated rounds 5/6/7).
#define B03  2.5e-5f      // g vs 0.3            -> element fix (tier 1)
#define B01  2.5e-5f      // |comp| vs 0.1       -> element fix (tier 1)
#define B2   5e-6         // tier-1 residual band -> tier-2 full fp64 fix
#define BDYN 3e-5f        // |dyn| vs thr        -> row fp64 redo (row_exact)

// ---------------------------------------------------------------------------
// Shared 128x128x16 fp32 tile mainloop (validated rounds 2/3/5/6/7).
// ---------------------------------------------------------------------------
#define STAGE_STORE(B)                                                          \
        As[B][aq * 4 + 0][ar] = pa0.x; As[B][aq * 4 + 1][ar] = pa0.y;           \
        As[B][aq * 4 + 2][ar] = pa0.z; As[B][aq * 4 + 3][ar] = pa0.w;           \
        As[B][aq * 4 + 0][ar + 64] = pa1.x; As[B][aq * 4 + 1][ar + 64] = pa1.y; \
        As[B][aq * 4 + 2][ar + 64] = pa1.z; As[B][aq * 4 + 3][ar + 64] = pa1.w; \
        *(float4*)&Bs[B][bk][bn4] = pb0;                                        \
        *(float4*)&Bs[B][bk + 8][bn4] = pb1;

#define GEMM_MAINLOOP(Aptr, Wptr, Kdim, Ndim)                                   \
    __shared__ float As[2][TK][LDSW];                                           \
    __shared__ float Bs[2][TK][LDSW];                                           \
    const int tid = threadIdx.x;                                                \
    const int bm = blockIdx.x * TM;                                             \
    const int bn = blockIdx.y * TN;                                             \
    const int tx = tid & 15, ty = tid >> 4;                                     \
    const int ar = tid >> 2, aq = tid & 3;                                      \
    const int bk = tid >> 5, bn4 = (tid & 31) * 4;                              \
    float acc[2][2][4][4];                                                      \
    _Pragma("unroll") for (int a = 0; a < 2; ++a)                               \
    _Pragma("unroll") for (int b = 0; b < 2; ++b)                               \
    _Pragma("unroll") for (int i = 0; i < 4; ++i)                               \
    _Pragma("unroll") for (int j = 0; j < 4; ++j) acc[a][b][i][j] = 0.f;        \
    float4 pa0 = *(const float4*)((Aptr) + (size_t)(bm + ar) * (Kdim) + aq * 4);      \
    float4 pa1 = *(const float4*)((Aptr) + (size_t)(bm + ar + 64) * (Kdim) + aq * 4); \
    float4 pb0 = *(const float4*)((Wptr) + (size_t)bk * (Ndim) + bn + bn4);           \
    float4 pb1 = *(const float4*)((Wptr) + (size_t)(bk + 8) * (Ndim) + bn + bn4);     \
    STAGE_STORE(0)                                                              \
    __syncthreads();                                                            \
    int buf = 0;                                                                \
    for (int k0 = 0; k0 < (Kdim); k0 += TK) {                                   \
        const int nk = k0 + TK;                                                 \
        if (nk < (Kdim)) {                                                      \
            pa0 = *(const float4*)((Aptr) + (size_t)(bm + ar) * (Kdim) + nk + aq * 4);      \
            pa1 = *(const float4*)((Aptr) + (size_t)(bm + ar + 64) * (Kdim) + nk + aq * 4); \
            pb0 = *(const float4*)((Wptr) + (size_t)(nk + bk) * (Ndim) + bn + bn4);         \
            pb1 = *(const float4*)((Wptr) + (size_t)(nk + bk + 8) * (Ndim) + bn + bn4);     \
        }                                                                       \
        _Pragma("unroll") for (int k = 0; k < TK; ++k) {                        \
            float4 da0 = *(const float4*)&As[buf][k][ty * 4];                   \
            float4 da1 = *(const float4*)&As[buf][k][64 + ty * 4];              \
            float4 db0 = *(const float4*)&Bs[buf][k][tx * 4];                   \
            float4 db1 = *(const float4*)&Bs[buf][k][64 + tx * 4];              \
            const float* dap[2] = {&da0.x, &da1.x};                             \
            const float* dbp[2] = {&db0.x, &db1.x};                             \
            _Pragma("unroll") for (int a = 0; a < 2; ++a)                       \
            _Pragma("unroll") for (int b = 0; b < 2; ++b)                       \
            _Pragma("unroll") for (int i = 0; i < 4; ++i)                       \
            _Pragma("unroll") for (int j = 0; j < 4; ++j)                       \
                acc[a][b][i][j] = fmaf(dap[a][i], dbp[b][j], acc[a][b][i][j]);  \
        }                                                                       \
        if (nk < (Kdim)) {                                                      \
            const int nb = buf ^ 1;                                             \
            STAGE_STORE(nb)                                                     \
            __syncthreads();                                                    \
            buf = nb;                                                           \
        }                                                                       \
    }

// ---------------------------------------------------------------------------
// K1: h1 = relu(F @ Wg1 + b1), fp32.
// ---------------------------------------------------------------------------
__global__ __launch_bounds__(256) void gemm1_f32(
    const float* __restrict__ A, const float* __restrict__ W,
    const float* __restrict__ bias, float* __restrict__ out, int M)
{
    const int K = 1024, N = 256;
    GEMM_MAINLOOP(A, W, K, N)
    #pragma unroll
    for (int a = 0; a < 2; ++a) {
        #pragma unroll
        for (int b = 0; b < 2; ++b) {
            const int col = bn + b * 64 + tx * 4;
            float4 bi = *(const float4*)(bias + col);
            #pragma unroll
            for (int i = 0; i < 4; ++i) {
                const int row = bm + a * 64 + ty * 4 + i;
                float4 o;
                o.x = fmaxf(acc[a][b][i][0] + bi.x, 0.f);
                o.y = fmaxf(acc[a][b][i][1] + bi.y, 0.f);
                o.z = fmaxf(acc[a][b][i][2] + bi.z, 0.f);
                o.w = fmaxf(acc[a][b][i][3] + bi.w, 0.f);
                *(float4*)(out + (size_t)row * N + col) = o;
            }
        }
    }
}

// ---------------------------------------------------------------------------
// K2: z2 = h1 @ Wg2 + b2; g = F * sigmoid(z2); comp = (g>0.3)?0:g.
// fp32 epilogue.  Near-boundary elements -> elist1 for the tiered fp64 fix.
// ---------------------------------------------------------------------------
__global__ __launch_bounds__(256) void gemm2_f32(
    const float* __restrict__ A, const float* __restrict__ W,
    const float* __restrict__ bias, const float* __restrict__ F,
    float* __restrict__ out, unsigned* __restrict__ ectr1,
    uint2* __restrict__ elist1, int M)
{
    const int K = 256, N = 1024;
    GEMM_MAINLOOP(A, W, K, N)
    #pragma unroll
    for (int a = 0; a < 2; ++a) {
        #pragma unroll
        for (int b = 0; b < 2; ++b) {
            const int col = bn + b * 64 + tx * 4;
            float4 bi = *(const float4*)(bias + col);
            const float* bip = &bi.x;
            #pragma unroll
            for (int i = 0; i < 4; ++i) {
                const int row = bm + a * 64 + ty * 4 + i;
                float4 fv = *(const float4*)(F + (size_t)row * N + col);
                const float* fvp = &fv.x;
                float4 o;
                float* op = &o.x;
                #pragma unroll
                for (int j = 0; j < 4; ++j) {
                    float z = acc[a][b][i][j] + bip[j];
                    float gw = 1.0f / (1.0f + __expf(-z));
                    float g = fvp[j] * gw;
                    float c = (g > 0.3f) ? 0.f : g;
                    if (fabsf(g - 0.3f) < B03 || fabsf(fabsf(c) - 0.1f) < B01) {
                        unsigned idx = atomicAdd(ectr1, 1u);
                        if (idx < FIXCAP) elist1[idx] = make_uint2((unsigned)row, (unsigned)(col + j));
                    }
                    op[j] = c;
                }
                *(float4*)(out + (size_t)row * N + col) = o;
            }
        }
    }
}

// ---------------------------------------------------------------------------
// fix_near (tier 1): refine flagged elements with an fp64 dot of the STORED
// fp32 h1 row and the Wg2 column.  Escalate still-near elements to fix_full.
// ---------------------------------------------------------------------------
__global__ __launch_bounds__(256) void fix_near(
    const float* __restrict__ h1, const float* __restrict__ F,
    const float* __restrict__ Wg2, const float* __restrict__ bg2,
    const unsigned* __restrict__ ectr1, const uint2* __restrict__ elist1,
    unsigned* __restrict__ ectr2, uint2* __restrict__ elist2,
    float* __restrict__ out, int* __restrict__ corr)
{
    __shared__ double red[4];
    const int tid = threadIdx.x;
    unsigned cnt = *ectr1;
    if (cnt > FIXCAP) cnt = FIXCAP;

    for (unsigned e = blockIdx.x; e < cnt; e += gridDim.x) {
        const unsigned row = elist1[e].x, col = elist1[e].y;
        double p = (double)h1[(size_t)row * 256 + tid]
                 * (double)Wg2[(size_t)tid * 1024 + col];
        #pragma unroll
        for (int o = 32; o > 0; o >>= 1) p += __shfl_down(p, o, 64);
        if ((tid & 63) == 0) red[tid >> 6] = p;
        __syncthreads();
        if (tid == 0) {
            double z2 = red[0] + red[1] + red[2] + red[3] + (double)bg2[col];
            double gw = 1.0 / (1.0 + exp(-z2));
            double g = (double)F[(size_t)row * 1024 + col] * gw;
            double c = (g > 0.3) ? 0.0 : g;
            bool near = (fabs(g - 0.3) < B2) || (fabs(fabs(c) - 0.1) < B2);
            if (near) {
                unsigned i2 = atomicAdd(ectr2, 1u);
                if (i2 < FIXCAP) elist2[i2] = make_uint2(row, col);
            } else {
                float cf = (float)c;
                int d_ref = (fabs(c) < 0.1) ? 1 : 0;
                int d_st  = (fabsf(cf) < 0.1f) ? 1 : 0;
                if (d_ref != d_st) atomicAdd(&corr[row], d_ref - d_st);
                out[(size_t)row * 1024 + col] = cf;
            }
        }
        __syncthreads();
    }
}

// ---------------------------------------------------------------------------
// Double-buffered 16KB weight-tile pipeline pieces (GEMM-mainloop pattern:
// reg-prefetch tile t+1 while computing tile t from LDS, one barrier/tile).
// Tile = 4096 consecutive floats of the weight matrix.
// ---------------------------------------------------------------------------
#define WT_PREFETCH(ptr)                                                        \
            r0 = *(const float4*)((ptr) + 0 * 1024 + tid * 4);                  \
            r1 = *(const float4*)((ptr) + 1 * 1024 + tid * 4);                  \
            r2 = *(const float4*)((ptr) + 2 * 1024 + tid * 4);                  \
            r3 = *(const float4*)((ptr) + 3 * 1024 + tid * 4);

#define WT_STORE(B)                                                             \
            *(float4*)&Wt[B][0 * 1024 + tid * 4] = r0;                          \
            *(float4*)&Wt[B][1 * 1024 + tid * 4] = r1;                          \
            *(float4*)&Wt[B][2 * 1024 + tid * 4] = r2;                          \
            *(float4*)&Wt[B][3 * 1024 + tid * 4] = r3;

// ---------------------------------------------------------------------------
// fix_full (tier 2): true fp64 recompute from F.  ROUND-8: wg1 pass uses the
// dbuf reg-prefetch tile pipeline (staging latency hidden behind compute).
// fp64 summation-order delta ~1e-14 (same class as validated r6/r7 changes).
// ---------------------------------------------------------------------------
__global__ __launch_bounds__(256) void fix_full(
    const float* __restrict__ F, const float* __restrict__ Wg1,
    const float* __restrict__ bg1, const float* __restrict__ Wg2,
    const float* __restrict__ bg2,
    const unsigned* __restrict__ ectr2, const uint2* __restrict__ elist2,
    float* __restrict__ out, int* __restrict__ corr)
{
    __shared__ float Fs[1024];
    __shared__ float Wt[2][4096];
    __shared__ double red[4];
    const int tid = threadIdx.x;
    unsigned cnt = *ectr2;
    if (cnt > FIXCAP) cnt = FIXCAP;

    for (unsigned e = blockIdx.x; e < cnt; e += gridDim.x) {
        const unsigned row = elist2[e].x, col = elist2[e].y;
        __syncthreads();
        *(float4*)&Fs[tid * 4] = *(const float4*)(F + (size_t)row * 1024 + tid * 4);

        float4 r0, r1, r2, r3;
        WT_PREFETCH(Wg1)
        WT_STORE(0)
        __syncthreads();
        double p0 = 0.0, p1 = 0.0, p2 = 0.0, p3 = 0.0;
        int buf = 0;
        for (int t = 0; t < 64; ++t) {
            if (t + 1 < 64) { const float* np = Wg1 + (size_t)(t + 1) * 4096; WT_PREFETCH(np) }
            const int kb = t * 16;
            #pragma unroll
            for (int kk = 0; kk < 16; kk += 4) {
                p0 += (double)Fs[kb + kk + 0] * (double)Wt[buf][(kk + 0) * 256 + tid];
                p1 += (double)Fs[kb + kk + 1] * (double)Wt[buf][(kk + 1) * 256 + tid];
                p2 += (double)Fs[kb + kk + 2] * (double)Wt[buf][(kk + 2) * 256 + tid];
                p3 += (double)Fs[kb + kk + 3] * (double)Wt[buf][(kk + 3) * 256 + tid];
            }
            if (t + 1 < 64) {
                const int nb = buf ^ 1;
                WT_STORE(nb)
                __syncthreads();
                buf = nb;
            }
        }
        double h = ((p0 + p1) + (p2 + p3)) + (double)bg1[tid];
        h = (h > 0.0) ? h : 0.0;
        double p = h * (double)Wg2[(size_t)tid * 1024 + col];
        #pragma unroll
        for (int o = 32; o > 0; o >>= 1) p += __shfl_down(p, o, 64);
        if ((tid & 63) == 0) red[tid >> 6] = p;
        __syncthreads();
        if (tid == 0) {
            double z2 = red[0] + red[1] + red[2] + red[3] + (double)bg2[col];
            double gw = 1.0 / (1.0 + exp(-z2));
            double g = (double)Fs[col] * gw;
            double c = (g > 0.3) ? 0.0 : g;
            float cf = (float)c;
            int d_ref = (fabs(c) < 0.1) ? 1 : 0;
            int d_st  = (fabsf(cf) < 0.1f) ? 1 : 0;
            if (d_ref != d_st) atomicAdd(&corr[row], d_ref - d_st);
            out[(size_t)row * 1024 + col] = cf;
        }
    }
}

// ---------------------------------------------------------------------------
// K3: per-row finalize (unchanged, validated rounds 5/6/7).
// ---------------------------------------------------------------------------
__global__ __launch_bounds__(256) void finalize_rows(
    float* __restrict__ C,
    const float* __restrict__ wr1, const float* __restrict__ br1,
    const float* __restrict__ wr2, const float* __restrict__ br2,
    const float* __restrict__ wm1, const float* __restrict__ bm1,
    const float* __restrict__ wm2, const float* __restrict__ bm2,
    const int* __restrict__ corr,
    unsigned* __restrict__ rctr, unsigned* __restrict__ rowlist)
{
    const int D = 1024;
    const int tid = threadIdx.x;
    const int lane = tid & 63;
    const unsigned row = blockIdx.x * 4 + (tid >> 6);
    const size_t base = (size_t)row * D;
    const int col0 = lane * 4;

    float4 c4[4];
    #pragma unroll
    for (int q = 0; q < 4; ++q)
        c4[q] = *(const float4*)(C + base + q * 256 + col0);

    float c[16];
    #pragma unroll
    for (int q = 0; q < 4; ++q) {
        c[q * 4 + 0] = c4[q].x; c[q * 4 + 1] = c4[q].y;
        c[q * 4 + 2] = c4[q].z; c[q * 4 + 3] = c4[q].w;
    }

    float cnt = 0.f;
    #pragma unroll
    for (int i = 0; i < 16; ++i) cnt += (fabsf(c[i]) < 0.1f) ? 1.f : 0.f;
    #pragma unroll
    for (int o = 32; o > 0; o >>= 1) cnt += __shfl_xor(cnt, o, 64);
    cnt += (float)corr[row];
    const double cur_sp = (double)cnt / 1024.0;

    float hid[16];
    #pragma unroll
    for (int h = 0; h < 16; ++h) {
        double z = cur_sp * (double)wr1[h] + 0.1 * (double)wr1[16 + h] + (double)br1[h];
        hid[h] = (float)((z > 0.0) ? z : 0.0);
    }

    float dyn[16];
    #pragma unroll
    for (int q = 0; q < 4; ++q) {
        const int cq = q * 256 + col0;
        float4 b4 = *(const float4*)(br2 + cq);
        float z[4] = {b4.x, b4.y, b4.z, b4.w};
        #pragma unroll
        for (int h = 0; h < 16; ++h) {
            float4 w4 = *(const float4*)(wr2 + (size_t)h * D + cq);
            z[0] = fmaf(hid[h], w4.x, z[0]);
            z[1] = fmaf(hid[h], w4.y, z[1]);
            z[2] = fmaf(hid[h], w4.z, z[2]);
            z[3] = fmaf(hid[h], w4.w, z[3]);
        }
        #pragma unroll
        for (int j = 0; j < 4; ++j) {
            float rw = 1.0f / (1.0f + __expf(-z[j]));
            dyn[q * 4 + j] = c[q * 4 + j] * rw;
        }
    }

    float s = 0.f, mx = -1e30f;
    #pragma unroll
    for (int i = 0; i < 16; ++i) { s += dyn[i]; mx = fmaxf(mx, dyn[i]); }
    #pragma unroll
    for (int o = 32; o > 0; o >>= 1) s += __shfl_xor(s, o, 64);
    const float mean = s / 1024.0f;

    float sq = 0.f;
    #pragma unroll
    for (int i = 0; i < 16; ++i) { float d = dyn[i] - mean; sq = fmaf(d, d, sq); }
    #pragma unroll
    for (int o = 32; o > 0; o >>= 1) sq += __shfl_xor(sq, o, 64);
    const float sd = sqrtf(sq / 1023.0f);

    #pragma unroll
    for (int o = 32; o > 0; o >>= 1) mx = fmaxf(mx, __shfl_xor(mx, o, 64));

    double acc2 = (double)bm2[0];
    #pragma unroll
    for (int h = 0; h < 16; ++h) {
        double hz = (double)mean * (double)wm1[h] + (double)sd * (double)wm1[16 + h]
                  + (double)mx * (double)wm1[32 + h] + (double)bm1[h];
        hz = (hz > 0.0) ? hz : 0.0;
        acc2 += hz * (double)wm2[h];
    }
    const float thr = (float)(1.0 / (1.0 + exp(-acc2)));

    bool fl = false;
    #pragma unroll
    for (int i = 0; i < 16; ++i)
        if (fabsf(fabsf(dyn[i]) - thr) < BDYN) fl = true;

    if (__any(fl)) {
        if (lane == 0) {
            unsigned idx = atomicAdd(rctr, 1u);
            if (idx < ROWCAP) rowlist[idx] = row;
        }
        return;                         // preserve comp row for row_exact
    }

    #pragma unroll
    for (int q = 0; q < 4; ++q) {
        float4 o4;
        float* op = &o4.x;
        #pragma unroll
        for (int j = 0; j < 4; ++j) {
            float d = dyn[q * 4 + j];
            op[j] = (fabsf(d) > thr) ? d : 0.f;
        }
        *(float4*)(C + base + q * 256 + col0) = o4;
    }
}

// ---------------------------------------------------------------------------
// fp64 block reduction helper (256 threads).
// ---------------------------------------------------------------------------
__device__ __forceinline__ double block_reduce_d(double v, double* sm, int tid, int op)
{
    #pragma unroll
    for (int o = 32; o > 0; o >>= 1) {
        double other = __shfl_down(v, o, 64);
        v = op ? fmax(v, other) : (v + other);
    }
    if ((tid & 63) == 0) sm[tid >> 6] = v;
    __syncthreads();
    if (tid == 0) {
        double r = sm[0];
        for (int w = 1; w < 4; ++w) r = op ? fmax(r, sm[w]) : (r + sm[w]);
        sm[4] = r;
    }
    __syncthreads();
    double r = sm[4];
    __syncthreads();
    return r;
}

// ---------------------------------------------------------------------------
// row_exact: full fp64 recompute of the ENTIRE pipeline from F for rows near
// the mask boundary.  ROUND-8 perf restructure: both weight streams use the
// dbuf reg-prefetch 16KB-tile pipeline (GEMM-mainloop pattern) so staging
// latency hides behind fp64 compute — the r7 structure exposed full load
// latency on all 64 rounds (263us/row, VALUBusy 8.5%).  4-chain h1 partials
// shorten the fp64 dependency chain.  Order delta ~1e-14 (validated class).
// ---------------------------------------------------------------------------
__global__ __launch_bounds__(256) void row_exact(
    const float* __restrict__ F,
    const float* __restrict__ wg1, const float* __restrict__ bg1,
    const float* __restrict__ wg2, const float* __restrict__ bg2,
    const float* __restrict__ wr1, const float* __restrict__ br1,
    const float* __restrict__ wr2, const float* __restrict__ br2,
    const float* __restrict__ wm1, const float* __restrict__ bm1,
    const float* __restrict__ wm2, const float* __restrict__ bm2,
    const unsigned* __restrict__ rctr, const unsigned* __restrict__ rowlist,
    float* __restrict__ out)
{
    __shared__ float  Fs[1024];
    __shared__ float  Wt[2][4096];   // 2 x 16KB tiles
    __shared__ double h1d[256];
    __shared__ double sm[8];
    const int tid = threadIdx.x;
    unsigned rcnt = *rctr;
    if (rcnt > ROWCAP) rcnt = ROWCAP;

    for (unsigned e = blockIdx.x; e < rcnt; e += gridDim.x) {
        const unsigned row = rowlist[e];
        __syncthreads();                // protect Fs/h1d/Wt reuse across rows
        *(float4*)&Fs[tid * 4] = *(const float4*)(F + (size_t)row * 1024 + tid * 4);

        // ---- h1 phase: 64 dbuf tiles of wg1 (16 k-rows each) ----
        {
            float4 r0, r1, r2, r3;
            WT_PREFETCH(wg1)
            WT_STORE(0)
            __syncthreads();            // Fs + tile0 visible
            double p0 = 0.0, p1 = 0.0, p2 = 0.0, p3 = 0.0;
            int buf = 0;
            for (int t = 0; t < 64; ++t) {
                if (t + 1 < 64) { const float* np = wg1 + (size_t)(t + 1) * 4096; WT_PREFETCH(np) }
                const int kb = t * 16;
                #pragma unroll
                for (int kk = 0; kk < 16; kk += 4) {
                    p0 += (double)Fs[kb + kk + 0] * (double)Wt[buf][(kk + 0) * 256 + tid];
                    p1 += (double)Fs[kb + kk + 1] * (double)Wt[buf][(kk + 1) * 256 + tid];
                    p2 += (double)Fs[kb + kk + 2] * (double)Wt[buf][(kk + 2) * 256 + tid];
                    p3 += (double)Fs[kb + kk + 3] * (double)Wt[buf][(kk + 3) * 256 + tid];
                }
                if (t + 1 < 64) {
                    const int nb = buf ^ 1;
                    WT_STORE(nb)
                    __syncthreads();
                    buf = nb;
                }
            }
            double a = ((p0 + p1) + (p2 + p3)) + (double)bg1[tid];
            h1d[tid] = (a > 0.0) ? a : 0.0;
        }
        __syncthreads();                // h1d visible; Wt free for reuse

        // ---- z2 phase: 64 dbuf tiles of wg2 (4 k-rows each) ----
        const int c0 = tid * 4;
        double zA[4] = {0.0, 0.0, 0.0, 0.0};
        double zB[4] = {0.0, 0.0, 0.0, 0.0};
        {
            float4 r0, r1, r2, r3;
            WT_PREFETCH(wg2)
            WT_STORE(0)
            __syncthreads();
            int buf = 0;
            for (int t = 0; t < 64; ++t) {
                if (t + 1 < 64) { const float* np = wg2 + (size_t)(t + 1) * 4096; WT_PREFETCH(np) }
                const int jb = t * 4;
                #pragma unroll
                for (int kk = 0; kk < 4; kk += 2) {
                    float4 wA = *(const float4*)&Wt[buf][(kk + 0) * 1024 + c0];
                    float4 wB = *(const float4*)&Wt[buf][(kk + 1) * 1024 + c0];
                    double hA = h1d[jb + kk], hB = h1d[jb + kk + 1];
                    zA[0] += hA * (double)wA.x; zA[1] += hA * (double)wA.y;
                    zA[2] += hA * (double)wA.z; zA[3] += hA * (double)wA.w;
                    zB[0] += hB * (double)wB.x; zB[1] += hB * (double)wB.y;
                    zB[2] += hB * (double)wB.z; zB[3] += hB * (double)wB.w;
                }
                if (t + 1 < 64) {
                    const int nb = buf ^ 1;
                    WT_STORE(nb)
                    __syncthreads();
                    buf = nb;
                }
            }
        }
        double comp[4];
        double cnt = 0.0;
        #pragma unroll
        for (int j = 0; j < 4; ++j) {
            double z2v = (double)bg2[c0 + j] + zA[j] + zB[j];
            double gw = 1.0 / (1.0 + exp(-z2v));
            double g = (double)Fs[c0 + j] * gw;
            double cm = (g > 0.3) ? 0.0 : g;
            comp[j] = cm;
            cnt += (fabs(cm) < 0.1) ? 1.0 : 0.0;
        }
        cnt = block_reduce_d(cnt, sm, tid, 0);
        const double cur_sp = cnt / 1024.0;

        double hid[16];
        #pragma unroll
        for (int h = 0; h < 16; ++h) {
            double hz = cur_sp * (double)wr1[h] + 0.1 * (double)wr1[16 + h] + (double)br1[h];
            hid[h] = (hz > 0.0) ? hz : 0.0;
        }
        double zr[4] = {(double)br2[c0], (double)br2[c0 + 1],
                        (double)br2[c0 + 2], (double)br2[c0 + 3]};
        #pragma unroll
        for (int h = 0; h < 16; ++h) {
            float4 w4 = *(const float4*)(wr2 + (size_t)h * 1024 + c0);
            zr[0] += hid[h] * (double)w4.x; zr[1] += hid[h] * (double)w4.y;
            zr[2] += hid[h] * (double)w4.z; zr[3] += hid[h] * (double)w4.w;
        }
        double dyn[4];
        #pragma unroll
        for (int j = 0; j < 4; ++j) {
            double rw = 1.0 / (1.0 + exp(-zr[j]));
            dyn[j] = comp[j] * rw;
        }

        double s = dyn[0] + dyn[1] + dyn[2] + dyn[3];
        s = block_reduce_d(s, sm, tid, 0);
        const double mean = s / 1024.0;

        double sq = 0.0;
        #pragma unroll
        for (int j = 0; j < 4; ++j) { double d = dyn[j] - mean; sq += d * d; }
        sq = block_reduce_d(sq, sm, tid, 0);
        const double sd = sqrt(sq / 1023.0);

        double mx = fmax(fmax(dyn[0], dyn[1]), fmax(dyn[2], dyn[3]));
        mx = block_reduce_d(mx, sm, tid, 1);

        double acc2 = (double)bm2[0];
        #pragma unroll
        for (int h = 0; h < 16; ++h) {
            double hz = mean * (double)wm1[h] + sd * (double)wm1[16 + h]
                      + mx * (double)wm1[32 + h] + (double)bm1[h];
            hz = (hz > 0.0) ? hz : 0.0;
            acc2 += hz * (double)wm2[h];
        }
        const double thr = 1.0 / (1.0 + exp(-acc2));

        float4 o4;
        o4.x = (float)((fabs(dyn[0]) > thr) ? dyn[0] : 0.0);
        o4.y = (float)((fabs(dyn[1]) > thr) ? dyn[1] : 0.0);
        o4.z = (float)((fabs(dyn[2]) > thr) ? dyn[2] : 0.0);
        o4.w = (float)((fabs(dyn[3]) > thr) ? dyn[3] : 0.0);
        *(float4*)(out + (size_t)row * 1024 + c0) = o4;
    }
}

// ---------------------------------------------------------------------------
extern "C" void kernel_launch(void* const* d_in, const int* in_sizes, int n_in,
                              void* d_out, int out_size, void* d_ws, size_t ws_size,
                              hipStream_t stream)
{
    const float* F   = (const float*)d_in[0];
    const float* wg1 = (const float*)d_in[1];
    const float* bg1 = (const float*)d_in[2];
    const float* wg2 = (const float*)d_in[3];
    const float* bg2 = (const float*)d_in[4];
    // d_in[5..8]: competition calculator — provably dead (win == False always)
    const float* wr1 = (const float*)d_in[9];
    const float* br1 = (const float*)d_in[10];
    const float* wr2 = (const float*)d_in[11];
    const float* br2 = (const float*)d_in[12];
    const float* wm1 = (const float*)d_in[13];
    const float* bm1 = (const float*)d_in[14];
    const float* wm2 = (const float*)d_in[15];
    const float* bm2 = (const float*)d_in[16];

    float* out = (float*)d_out;
    const int M = in_sizes[0] / 1024;                      // 32768

    char* ws = (char*)d_ws;
    float*    h1      = (float*)ws;                              // 32 MiB
    uint2*    elist1  = (uint2*)(ws + (32u << 20));              // 2 MiB
    uint2*    elist2  = (uint2*)(ws + (34u << 20));              // 2 MiB
    unsigned* rowlist = (unsigned*)(ws + (36u << 20));           // 128 KiB
    int*      corr    = (int*)(ws + (36u << 20) + (128u << 10)); // 128 KiB
    unsigned* ctrs    = (unsigned*)(ws + (36u << 20) + (256u << 10));
    unsigned* ectr1 = ctrs, *ectr2 = ctrs + 1, *rctr = ctrs + 2;

    // zero corr + counters in one shot (contiguous)
    hipMemsetAsync(corr, 0, (size_t)M * sizeof(int) + 16, stream);
    gemm1_f32<<<dim3(M / TM, 256 / TN), 256, 0, stream>>>(F, wg1, bg1, h1, M);
    gemm2_f32<<<dim3(M / TM, 1024 / TN), 256, 0, stream>>>(h1, wg2, bg2, F, out, ectr1, elist1, M);
    fix_near<<<2048, 256, 0, stream>>>(h1, F, wg2, bg2, ectr1, elist1, ectr2, elist2, out, corr);
    fix_full<<<1024, 256, 0, stream>>>(F, wg1, bg1, wg2, bg2, ectr2, elist2, out, corr);
    finalize_rows<<<M / 4, 256, 0, stream>>>(out, wr1, br1, wr2, br2, wm1, bm1, wm2, bm2,
                                             corr, rctr, rowlist);
    row_exact<<<2048, 256, 0, stream>>>(F, wg1, bg1, wg2, bg2, wr1, br1, wr2, br2,
                                        wm1, bm1, wm2, bm2, rctr, rowlist, out);
}

// Round 10
// 908.991 us; speedup vs baseline: 1.9186x; 1.0568x over previous
//
#include <hip/hip_runtime.h>
#include <cmath>

#define TM 128
#define TN 128
#define TK 16
#define LDSW 132          // padded LDS row width (floats)
#define FIXCAP  262144u   // elist1 cap (2 MiB)
#define FIXCAP2 131072u   // elist2 cap (1 MiB; tier-2 escalations are ~dozens)
#define ROWCAP 32768u

// Decision-boundary protection bands (UNCHANGED from validated rounds 5-8).
// gemm2's bf16-split fast path has z2 error sigma ~4e-6 -> err(g) ~1e-6
// typical; bands keep >=6-sigma margins on all discrete decisions.
#define B03  2.5e-5f      // g vs 0.3            -> element fix (tier 1)
#define B01  2.5e-5f      // |comp| vs 0.1       -> element fix (tier 1)
#define B2   5e-6         // tier-1 residual band -> tier-2 full fp64 fix
#define BDYN 3e-5f        // |dyn| vs thr        -> row fp64 redo (row_exact)

typedef __attribute__((ext_vector_type(8))) short bf16x8;     // 8 bf16 = 4 VGPR
typedef __attribute__((ext_vector_type(8))) unsigned short ushort8;
typedef __attribute__((ext_vector_type(4))) float f32x4;

__device__ __forceinline__ unsigned short bf16_rne(float x)
{
    unsigned u = __float_as_uint(x);
    unsigned r = u + 0x7FFFu + ((u >> 16) & 1u);
    return (unsigned short)(r >> 16);
}
__device__ __forceinline__ float bf16_to_f(unsigned short h)
{
    return __uint_as_float(((unsigned)h) << 16);
}

// ---------------------------------------------------------------------------
// Shared 128x128x16 fp32 tile mainloop (validated rounds 2-8) — used by K1.
// ---------------------------------------------------------------------------
#define STAGE_STORE(B)                                                          \
        As[B][aq * 4 + 0][ar] = pa0.x; As[B][aq * 4 + 1][ar] = pa0.y;           \
        As[B][aq * 4 + 2][ar] = pa0.z; As[B][aq * 4 + 3][ar] = pa0.w;           \
        As[B][aq * 4 + 0][ar + 64] = pa1.x; As[B][aq * 4 + 1][ar + 64] = pa1.y; \
        As[B][aq * 4 + 2][ar + 64] = pa1.z; As[B][aq * 4 + 3][ar + 64] = pa1.w; \
        *(float4*)&Bs[B][bk][bn4] = pb0;                                        \
        *(float4*)&Bs[B][bk + 8][bn4] = pb1;

#define GEMM_MAINLOOP(Aptr, Wptr, Kdim, Ndim)                                   \
    __shared__ float As[2][TK][LDSW];                                           \
    __shared__ float Bs[2][TK][LDSW];                                           \
    const int tid = threadIdx.x;                                                \
    const int bm = blockIdx.x * TM;                                             \
    const int bn = blockIdx.y * TN;                                             \
    const int tx = tid & 15, ty = tid >> 4;                                     \
    const int ar = tid >> 2, aq = tid & 3;                                      \
    const int bk = tid >> 5, bn4 = (tid & 31) * 4;                              \
    float acc[2][2][4][4];                                                      \
    _Pragma("unroll") for (int a = 0; a < 2; ++a)                               \
    _Pragma("unroll") for (int b = 0; b < 2; ++b)                               \
    _Pragma("unroll") for (int i = 0; i < 4; ++i)                               \
    _Pragma("unroll") for (int j = 0; j < 4; ++j) acc[a][b][i][j] = 0.f;        \
    float4 pa0 = *(const float4*)((Aptr) + (size_t)(bm + ar) * (Kdim) + aq * 4);      \
    float4 pa1 = *(const float4*)((Aptr) + (size_t)(bm + ar + 64) * (Kdim) + aq * 4); \
    float4 pb0 = *(const float4*)((Wptr) + (size_t)bk * (Ndim) + bn + bn4);           \
    float4 pb1 = *(const float4*)((Wptr) + (size_t)(bk + 8) * (Ndim) + bn + bn4);     \
    STAGE_STORE(0)                                                              \
    __syncthreads();                                                            \
    int buf = 0;                                                                \
    for (int k0 = 0; k0 < (Kdim); k0 += TK) {                                   \
        const int nk = k0 + TK;                                                 \
        if (nk < (Kdim)) {                                                      \
            pa0 = *(const float4*)((Aptr) + (size_t)(bm + ar) * (Kdim) + nk + aq * 4);      \
            pa1 = *(const float4*)((Aptr) + (size_t)(bm + ar + 64) * (Kdim) + nk + aq * 4); \
            pb0 = *(const float4*)((Wptr) + (size_t)(nk + bk) * (Ndim) + bn + bn4);         \
            pb1 = *(const float4*)((Wptr) + (size_t)(nk + bk + 8) * (Ndim) + bn + bn4);     \
        }                                                                       \
        _Pragma("unroll") for (int k = 0; k < TK; ++k) {                        \
            float4 da0 = *(const float4*)&As[buf][k][ty * 4];                   \
            float4 da1 = *(const float4*)&As[buf][k][64 + ty * 4];              \
            float4 db0 = *(const float4*)&Bs[buf][k][tx * 4];                   \
            float4 db1 = *(const float4*)&Bs[buf][k][64 + tx * 4];              \
            const float* dap[2] = {&da0.x, &da1.x};                             \
            const float* dbp[2] = {&db0.x, &db1.x};                             \
            _Pragma("unroll") for (int a = 0; a < 2; ++a)                       \
            _Pragma("unroll") for (int b = 0; b < 2; ++b)                       \
            _Pragma("unroll") for (int i = 0; i < 4; ++i)                       \
            _Pragma("unroll") for (int j = 0; j < 4; ++j)                       \
                acc[a][b][i][j] = fmaf(dap[a][i], dbp[b][j], acc[a][b][i][j]);  \
        }                                                                       \
        if (nk < (Kdim)) {                                                      \
            const int nb = buf ^ 1;                                             \
            STAGE_STORE(nb)                                                     \
            __syncthreads();                                                    \
            buf = nb;                                                           \
        }                                                                       \
    }

// ---------------------------------------------------------------------------
// K1: h1 = relu(F @ Wg1 + b1), fp32.  UNCHANGED (validated).
// ---------------------------------------------------------------------------
__global__ __launch_bounds__(256) void gemm1_f32(
    const float* __restrict__ A, const float* __restrict__ W,
    const float* __restrict__ bias, float* __restrict__ out, int M)
{
    const int K = 1024, N = 256;
    GEMM_MAINLOOP(A, W, K, N)
    #pragma unroll
    for (int a = 0; a < 2; ++a) {
        #pragma unroll
        for (int b = 0; b < 2; ++b) {
            const int col = bn + b * 64 + tx * 4;
            float4 bi = *(const float4*)(bias + col);
            #pragma unroll
            for (int i = 0; i < 4; ++i) {
                const int row = bm + a * 64 + ty * 4 + i;
                float4 o;
                o.x = fmaxf(acc[a][b][i][0] + bi.x, 0.f);
                o.y = fmaxf(acc[a][b][i][1] + bi.y, 0.f);
                o.z = fmaxf(acc[a][b][i][2] + bi.z, 0.f);
                o.w = fmaxf(acc[a][b][i][3] + bi.w, 0.f);
                *(float4*)(out + (size_t)row * N + col) = o;
            }
        }
    }
}

// ---------------------------------------------------------------------------
// split_wg2: wg2 [256 k][1024 n] fp32 -> wg2T_h / wg2T_l bf16 [1024 n][256 k]
// (transposed + 2-way split).  1 MB total; runs once, a few us.
// ---------------------------------------------------------------------------
__global__ __launch_bounds__(256) void split_wg2(
    const float* __restrict__ wg2, unsigned short* __restrict__ th,
    unsigned short* __restrict__ tl)
{
    const int n = blockIdx.x;      // 1024
    const int k = threadIdx.x;     // 256
    float x = wg2[(size_t)k * 1024 + n];
    unsigned short h = bf16_rne(x);
    th[(size_t)n * 256 + k] = h;
    tl[(size_t)n * 256 + k] = bf16_rne(x - bf16_to_f(h));
}

// ---------------------------------------------------------------------------
// K2 (MFMA): z2 = h1 @ Wg2 + b2 via bf16 split-2 on the matrix cores.
// a*b ~= ah*bh + ah*bl + al*bh, fp32 accumulate (3x mfma_f32_16x16x32_bf16).
// Block 128x128, 4 waves (2x2, each 64x64 = 4x4 tiles of 16x16).  K-step 32,
// single-buffered LDS (40 KB, pad->conflict-free b128 frag reads).
// Fragment layouts (gfx950, m89-verified): A row=lane&15, k=(lane>>4)*8+i;
// B col=lane&15, same k; D col=lane&15, row=(lane>>4)*4+reg.
// ---------------------------------------------------------------------------
__global__ __launch_bounds__(256) void gemm2_mfma(
    const float* __restrict__ h1, const unsigned short* __restrict__ bTh,
    const unsigned short* __restrict__ bTl, const float* __restrict__ bias,
    const float* __restrict__ F, float* __restrict__ out,
    unsigned* __restrict__ ectr1, uint2* __restrict__ elist1, int M)
{
    __shared__ __align__(16) unsigned short Ah[128][40];
    __shared__ __align__(16) unsigned short Al[128][40];
    __shared__ __align__(16) unsigned short Bh[128][40];
    __shared__ __align__(16) unsigned short Bl[128][40];

    const int tid  = threadIdx.x;
    const int lane = tid & 63;
    const int wave = tid >> 6;
    const int wr = wave >> 1, wc = wave & 1;
    const int bm = blockIdx.x * 128;
    const int bn = blockIdx.y * 128;

    f32x4 acc[4][4];
    #pragma unroll
    for (int mi = 0; mi < 4; ++mi)
        #pragma unroll
        for (int ni = 0; ni < 4; ++ni)
            acc[mi][ni] = (f32x4){0.f, 0.f, 0.f, 0.f};

    const int sr = tid >> 1;          // staging row 0..127
    const int sh = tid & 1;           // staging half (16-wide k chunk)

    for (int k0 = 0; k0 < 256; k0 += 32) {
        __syncthreads();
        // ---- stage A: h1 fp32 -> split bf16 ----
        {
            const float* src = h1 + (size_t)(bm + sr) * 256 + k0 + sh * 16;
            unsigned short* dh = &Ah[sr][sh * 16];
            unsigned short* dl = &Al[sr][sh * 16];
            #pragma unroll
            for (int i = 0; i < 2; ++i) {
                float4 f0 = ((const float4*)src)[2 * i + 0];
                float4 f1 = ((const float4*)src)[2 * i + 1];
                float xs[8] = {f0.x, f0.y, f0.z, f0.w, f1.x, f1.y, f1.z, f1.w};
                ushort8 vh, vl;
                #pragma unroll
                for (int j = 0; j < 8; ++j) {
                    unsigned short hh = bf16_rne(xs[j]);
                    vh[j] = hh;
                    vl[j] = bf16_rne(xs[j] - bf16_to_f(hh));
                }
                ((ushort8*)dh)[i] = vh;
                ((ushort8*)dl)[i] = vl;
            }
        }
        // ---- stage B: pre-split bf16 copies ----
        {
            const ushort8* s0 = (const ushort8*)(bTh + (size_t)(bn + sr) * 256 + k0 + sh * 16);
            const ushort8* s1 = (const ushort8*)(bTl + (size_t)(bn + sr) * 256 + k0 + sh * 16);
            ushort8* d0 = (ushort8*)&Bh[sr][sh * 16];
            ushort8* d1 = (ushort8*)&Bl[sr][sh * 16];
            d0[0] = s0[0]; d0[1] = s0[1];
            d1[0] = s1[0]; d1[1] = s1[1];
        }
        __syncthreads();

        const int ko = (lane >> 4) * 8;
        const int fr = lane & 15;
        bf16x8 ah[4], al[4], bh[4], bl[4];
        #pragma unroll
        for (int mi = 0; mi < 4; ++mi) {
            ah[mi] = *(const bf16x8*)&Ah[wr * 64 + mi * 16 + fr][ko];
            al[mi] = *(const bf16x8*)&Al[wr * 64 + mi * 16 + fr][ko];
        }
        #pragma unroll
        for (int ni = 0; ni < 4; ++ni) {
            bh[ni] = *(const bf16x8*)&Bh[wc * 64 + ni * 16 + fr][ko];
            bl[ni] = *(const bf16x8*)&Bl[wc * 64 + ni * 16 + fr][ko];
        }
        #pragma unroll
        for (int mi = 0; mi < 4; ++mi) {
            #pragma unroll
            for (int ni = 0; ni < 4; ++ni) {
                acc[mi][ni] = __builtin_amdgcn_mfma_f32_16x16x32_bf16(ah[mi], bh[ni], acc[mi][ni], 0, 0, 0);
                acc[mi][ni] = __builtin_amdgcn_mfma_f32_16x16x32_bf16(ah[mi], bl[ni], acc[mi][ni], 0, 0, 0);
                acc[mi][ni] = __builtin_amdgcn_mfma_f32_16x16x32_bf16(al[mi], bh[ni], acc[mi][ni], 0, 0, 0);
            }
        }
    }

    // ---- epilogue: sigmoid gate + threshold + band flags (fp32 fast path) ----
    #pragma unroll
    for (int ni = 0; ni < 4; ++ni) {
        const int col = bn + wc * 64 + ni * 16 + (lane & 15);
        const float bi = bias[col];
        #pragma unroll
        for (int mi = 0; mi < 4; ++mi) {
            #pragma unroll
            for (int r = 0; r < 4; ++r) {
                const int row = bm + wr * 64 + mi * 16 + (lane >> 4) * 4 + r;
                float z = acc[mi][ni][r] + bi;
                float gw = 1.0f / (1.0f + __expf(-z));
                float g = F[(size_t)row * 1024 + col] * gw;
                float c = (g > 0.3f) ? 0.f : g;
                if (fabsf(g - 0.3f) < B03 || fabsf(fabsf(c) - 0.1f) < B01) {
                    unsigned idx = atomicAdd(ectr1, 1u);
                    if (idx < FIXCAP) elist1[idx] = make_uint2((unsigned)row, (unsigned)col);
                }
                out[(size_t)row * 1024 + col] = c;
            }
        }
    }
}

// ---------------------------------------------------------------------------
// fix_near (tier 1): UNCHANGED (reads fp32 h1 — gemm1 untouched).
// ---------------------------------------------------------------------------
__global__ __launch_bounds__(256) void fix_near(
    const float* __restrict__ h1, const float* __restrict__ F,
    const float* __restrict__ Wg2, const float* __restrict__ bg2,
    const unsigned* __restrict__ ectr1, const uint2* __restrict__ elist1,
    unsigned* __restrict__ ectr2, uint2* __restrict__ elist2,
    float* __restrict__ out, int* __restrict__ corr)
{
    __shared__ double red[4];
    const int tid = threadIdx.x;
    unsigned cnt = *ectr1;
    if (cnt > FIXCAP) cnt = FIXCAP;

    for (unsigned e = blockIdx.x; e < cnt; e += gridDim.x) {
        const unsigned row = elist1[e].x, col = elist1[e].y;
        double p = (double)h1[(size_t)row * 256 + tid]
                 * (double)Wg2[(size_t)tid * 1024 + col];
        #pragma unroll
        for (int o = 32; o > 0; o >>= 1) p += __shfl_down(p, o, 64);
        if ((tid & 63) == 0) red[tid >> 6] = p;
        __syncthreads();
        if (tid == 0) {
            double z2 = red[0] + red[1] + red[2] + red[3] + (double)bg2[col];
            double gw = 1.0 / (1.0 + exp(-z2));
            double g = (double)F[(size_t)row * 1024 + col] * gw;
            double c = (g > 0.3) ? 0.0 : g;
            bool near = (fabs(g - 0.3) < B2) || (fabs(fabs(c) - 0.1) < B2);
            if (near) {
                unsigned i2 = atomicAdd(ectr2, 1u);
                if (i2 < FIXCAP2) elist2[i2] = make_uint2(row, col);
            } else {
                float cf = (float)c;
                int d_ref = (fabs(c) < 0.1) ? 1 : 0;
                int d_st  = (fabsf(cf) < 0.1f) ? 1 : 0;
                if (d_ref != d_st) atomicAdd(&corr[row], d_ref - d_st);
                out[(size_t)row * 1024 + col] = cf;
            }
        }
        __syncthreads();
    }
}

// ---------------------------------------------------------------------------
// dbuf 16KB weight-tile pipeline pieces (validated round 8).
// ---------------------------------------------------------------------------
#define WT_PREFETCH(ptr)                                                        \
            r0 = *(const float4*)((ptr) + 0 * 1024 + tid * 4);                  \
            r1 = *(const float4*)((ptr) + 1 * 1024 + tid * 4);                  \
            r2 = *(const float4*)((ptr) + 2 * 1024 + tid * 4);                  \
            r3 = *(const float4*)((ptr) + 3 * 1024 + tid * 4);

#define WT_STORE(B)                                                             \
            *(float4*)&Wt[B][0 * 1024 + tid * 4] = r0;                          \
            *(float4*)&Wt[B][1 * 1024 + tid * 4] = r1;                          \
            *(float4*)&Wt[B][2 * 1024 + tid * 4] = r2;                          \
            *(float4*)&Wt[B][3 * 1024 + tid * 4] = r3;

// ---------------------------------------------------------------------------
// fix_full (tier 2): UNCHANGED (validated round 8).
// ---------------------------------------------------------------------------
__global__ __launch_bounds__(256) void fix_full(
    const float* __restrict__ F, const float* __restrict__ Wg1,
    const float* __restrict__ bg1, const float* __restrict__ Wg2,
    const float* __restrict__ bg2,
    const unsigned* __restrict__ ectr2, const uint2* __restrict__ elist2,
    float* __restrict__ out, int* __restrict__ corr)
{
    __shared__ float Fs[1024];
    __shared__ float Wt[2][4096];
    __shared__ double red[4];
    const int tid = threadIdx.x;
    unsigned cnt = *ectr2;
    if (cnt > FIXCAP2) cnt = FIXCAP2;

    for (unsigned e = blockIdx.x; e < cnt; e += gridDim.x) {
        const unsigned row = elist2[e].x, col = elist2[e].y;
        __syncthreads();
        *(float4*)&Fs[tid * 4] = *(const float4*)(F + (size_t)row * 1024 + tid * 4);

        float4 r0, r1, r2, r3;
        WT_PREFETCH(Wg1)
        WT_STORE(0)
        __syncthreads();
        double p0 = 0.0, p1 = 0.0, p2 = 0.0, p3 = 0.0;
        int buf = 0;
        for (int t = 0; t < 64; ++t) {
            if (t + 1 < 64) { const float* np = Wg1 + (size_t)(t + 1) * 4096; WT_PREFETCH(np) }
            const int kb = t * 16;
            #pragma unroll
            for (int kk = 0; kk < 16; kk += 4) {
                p0 += (double)Fs[kb + kk + 0] * (double)Wt[buf][(kk + 0) * 256 + tid];
                p1 += (double)Fs[kb + kk + 1] * (double)Wt[buf][(kk + 1) * 256 + tid];
                p2 += (double)Fs[kb + kk + 2] * (double)Wt[buf][(kk + 2) * 256 + tid];
                p3 += (double)Fs[kb + kk + 3] * (double)Wt[buf][(kk + 3) * 256 + tid];
            }
            if (t + 1 < 64) {
                const int nb = buf ^ 1;
                WT_STORE(nb)
                __syncthreads();
                buf = nb;
            }
        }
        double h = ((p0 + p1) + (p2 + p3)) + (double)bg1[tid];
        h = (h > 0.0) ? h : 0.0;
        double p = h * (double)Wg2[(size_t)tid * 1024 + col];
        #pragma unroll
        for (int o = 32; o > 0; o >>= 1) p += __shfl_down(p, o, 64);
        if ((tid & 63) == 0) red[tid >> 6] = p;
        __syncthreads();
        if (tid == 0) {
            double z2 = red[0] + red[1] + red[2] + red[3] + (double)bg2[col];
            double gw = 1.0 / (1.0 + exp(-z2));
            double g = (double)Fs[col] * gw;
            double c = (g > 0.3) ? 0.0 : g;
            float cf = (float)c;
            int d_ref = (fabs(c) < 0.1) ? 1 : 0;
            int d_st  = (fabsf(cf) < 0.1f) ? 1 : 0;
            if (d_ref != d_st) atomicAdd(&corr[row], d_ref - d_st);
            out[(size_t)row * 1024 + col] = cf;
        }
    }
}

// ---------------------------------------------------------------------------
// K3: per-row finalize — UNCHANGED (validated rounds 5-8).
// ---------------------------------------------------------------------------
__global__ __launch_bounds__(256) void finalize_rows(
    float* __restrict__ C,
    const float* __restrict__ wr1, const float* __restrict__ br1,
    const float* __restrict__ wr2, const float* __restrict__ br2,
    const float* __restrict__ wm1, const float* __restrict__ bm1,
    const float* __restrict__ wm2, const float* __restrict__ bm2,
    const int* __restrict__ corr,
    unsigned* __restrict__ rctr, unsigned* __restrict__ rowlist)
{
    const int D = 1024;
    const int tid = threadIdx.x;
    const int lane = tid & 63;
    const unsigned row = blockIdx.x * 4 + (tid >> 6);
    const size_t base = (size_t)row * D;
    const int col0 = lane * 4;

    float4 c4[4];
    #pragma unroll
    for (int q = 0; q < 4; ++q)
        c4[q] = *(const float4*)(C + base + q * 256 + col0);

    float c[16];
    #pragma unroll
    for (int q = 0; q < 4; ++q) {
        c[q * 4 + 0] = c4[q].x; c[q * 4 + 1] = c4[q].y;
        c[q * 4 + 2] = c4[q].z; c[q * 4 + 3] = c4[q].w;
    }

    float cnt = 0.f;
    #pragma unroll
    for (int i = 0; i < 16; ++i) cnt += (fabsf(c[i]) < 0.1f) ? 1.f : 0.f;
    #pragma unroll
    for (int o = 32; o > 0; o >>= 1) cnt += __shfl_xor(cnt, o, 64);
    cnt += (float)corr[row];
    const double cur_sp = (double)cnt / 1024.0;

    float hid[16];
    #pragma unroll
    for (int h = 0; h < 16; ++h) {
        double z = cur_sp * (double)wr1[h] + 0.1 * (double)wr1[16 + h] + (double)br1[h];
        hid[h] = (float)((z > 0.0) ? z : 0.0);
    }

    float dyn[16];
    #pragma unroll
    for (int q = 0; q < 4; ++q) {
        const int cq = q * 256 + col0;
        float4 b4 = *(const float4*)(br2 + cq);
        float z[4] = {b4.x, b4.y, b4.z, b4.w};
        #pragma unroll
        for (int h = 0; h < 16; ++h) {
            float4 w4 = *(const float4*)(wr2 + (size_t)h * D + cq);
            z[0] = fmaf(hid[h], w4.x, z[0]);
            z[1] = fmaf(hid[h], w4.y, z[1]);
            z[2] = fmaf(hid[h], w4.z, z[2]);
            z[3] = fmaf(hid[h], w4.w, z[3]);
        }
        #pragma unroll
        for (int j = 0; j < 4; ++j) {
            float rw = 1.0f / (1.0f + __expf(-z[j]));
            dyn[q * 4 + j] = c[q * 4 + j] * rw;
        }
    }

    float s = 0.f, mx = -1e30f;
    #pragma unroll
    for (int i = 0; i < 16; ++i) { s += dyn[i]; mx = fmaxf(mx, dyn[i]); }
    #pragma unroll
    for (int o = 32; o > 0; o >>= 1) s += __shfl_xor(s, o, 64);
    const float mean = s / 1024.0f;

    float sq = 0.f;
    #pragma unroll
    for (int i = 0; i < 16; ++i) { float d = dyn[i] - mean; sq = fmaf(d, d, sq); }
    #pragma unroll
    for (int o = 32; o > 0; o >>= 1) sq += __shfl_xor(sq, o, 64);
    const float sd = sqrtf(sq / 1023.0f);

    #pragma unroll
    for (int o = 32; o > 0; o >>= 1) mx = fmaxf(mx, __shfl_xor(mx, o, 64));

    double acc2 = (double)bm2[0];
    #pragma unroll
    for (int h = 0; h < 16; ++h) {
        double hz = (double)mean * (double)wm1[h] + (double)sd * (double)wm1[16 + h]
                  + (double)mx * (double)wm1[32 + h] + (double)bm1[h];
        hz = (hz > 0.0) ? hz : 0.0;
        acc2 += hz * (double)wm2[h];
    }
    const float thr = (float)(1.0 / (1.0 + exp(-acc2)));

    bool fl = false;
    #pragma unroll
    for (int i = 0; i < 16; ++i)
        if (fabsf(fabsf(dyn[i]) - thr) < BDYN) fl = true;

    if (__any(fl)) {
        if (lane == 0) {
            unsigned idx = atomicAdd(rctr, 1u);
            if (idx < ROWCAP) rowlist[idx] = row;
        }
        return;                         // preserve comp row for row_exact
    }

    #pragma unroll
    for (int q = 0; q < 4; ++q) {
        float4 o4;
        float* op = &o4.x;
        #pragma unroll
        for (int j = 0; j < 4; ++j) {
            float d = dyn[q * 4 + j];
            op[j] = (fabsf(d) > thr) ? d : 0.f;
        }
        *(float4*)(C + base + q * 256 + col0) = o4;
    }
}

// ---------------------------------------------------------------------------
// fp64 block reduction helper (256 threads).
// ---------------------------------------------------------------------------
__device__ __forceinline__ double block_reduce_d(double v, double* sm, int tid, int op)
{
    #pragma unroll
    for (int o = 32; o > 0; o >>= 1) {
        double other = __shfl_down(v, o, 64);
        v = op ? fmax(v, other) : (v + other);
    }
    if ((tid & 63) == 0) sm[tid >> 6] = v;
    __syncthreads();
    if (tid == 0) {
        double r = sm[0];
        for (int w = 1; w < 4; ++w) r = op ? fmax(r, sm[w]) : (r + sm[w]);
        sm[4] = r;
    }
    __syncthreads();
    double r = sm[4];
    __syncthreads();
    return r;
}

// ---------------------------------------------------------------------------
// row_exact — UNCHANGED (validated round 8, dbuf tile pipeline).
// ---------------------------------------------------------------------------
__global__ __launch_bounds__(256) void row_exact(
    const float* __restrict__ F,
    const float* __restrict__ wg1, const float* __restrict__ bg1,
    const float* __restrict__ wg2, const float* __restrict__ bg2,
    const float* __restrict__ wr1, const float* __restrict__ br1,
    const float* __restrict__ wr2, const float* __restrict__ br2,
    const float* __restrict__ wm1, const float* __restrict__ bm1,
    const float* __restrict__ wm2, const float* __restrict__ bm2,
    const unsigned* __restrict__ rctr, const unsigned* __restrict__ rowlist,
    float* __restrict__ out)
{
    __shared__ float  Fs[1024];
    __shared__ float  Wt[2][4096];   // 2 x 16KB tiles
    __shared__ double h1d[256];
    __shared__ double sm[8];
    const int tid = threadIdx.x;
    unsigned rcnt = *rctr;
    if (rcnt > ROWCAP) rcnt = ROWCAP;

    for (unsigned e = blockIdx.x; e < rcnt; e += gridDim.x) {
        const unsigned row = rowlist[e];
        __syncthreads();
        *(float4*)&Fs[tid * 4] = *(const float4*)(F + (size_t)row * 1024 + tid * 4);

        {
            float4 r0, r1, r2, r3;
            WT_PREFETCH(wg1)
            WT_STORE(0)
            __syncthreads();
            double p0 = 0.0, p1 = 0.0, p2 = 0.0, p3 = 0.0;
            int buf = 0;
            for (int t = 0; t < 64; ++t) {
                if (t + 1 < 64) { const float* np = wg1 + (size_t)(t + 1) * 4096; WT_PREFETCH(np) }
                const int kb = t * 16;
                #pragma unroll
                for (int kk = 0; kk < 16; kk += 4) {
                    p0 += (double)Fs[kb + kk + 0] * (double)Wt[buf][(kk + 0) * 256 + tid];
                    p1 += (double)Fs[kb + kk + 1] * (double)Wt[buf][(kk + 1) * 256 + tid];
                    p2 += (double)Fs[kb + kk + 2] * (double)Wt[buf][(kk + 2) * 256 + tid];
                    p3 += (double)Fs[kb + kk + 3] * (double)Wt[buf][(kk + 3) * 256 + tid];
                }
                if (t + 1 < 64) {
                    const int nb = buf ^ 1;
                    WT_STORE(nb)
                    __syncthreads();
                    buf = nb;
                }
            }
            double a = ((p0 + p1) + (p2 + p3)) + (double)bg1[tid];
            h1d[tid] = (a > 0.0) ? a : 0.0;
        }
        __syncthreads();

        const int c0 = tid * 4;
        double zA[4] = {0.0, 0.0, 0.0, 0.0};
        double zB[4] = {0.0, 0.0, 0.0, 0.0};
        {
            float4 r0, r1, r2, r3;
            WT_PREFETCH(wg2)
            WT_STORE(0)
            __syncthreads();
            int buf = 0;
            for (int t = 0; t < 64; ++t) {
                if (t + 1 < 64) { const float* np = wg2 + (size_t)(t + 1) * 4096; WT_PREFETCH(np) }
                const int jb = t * 4;
                #pragma unroll
                for (int kk = 0; kk < 4; kk += 2) {
                    float4 wA = *(const float4*)&Wt[buf][(kk + 0) * 1024 + c0];
                    float4 wB = *(const float4*)&Wt[buf][(kk + 1) * 1024 + c0];
                    double hA = h1d[jb + kk], hB = h1d[jb + kk + 1];
                    zA[0] += hA * (double)wA.x; zA[1] += hA * (double)wA.y;
                    zA[2] += hA * (double)wA.z; zA[3] += hA * (double)wA.w;
                    zB[0] += hB * (double)wB.x; zB[1] += hB * (double)wB.y;
                    zB[2] += hB * (double)wB.z; zB[3] += hB * (double)wB.w;
                }
                if (t + 1 < 64) {
                    const int nb = buf ^ 1;
                    WT_STORE(nb)
                    __syncthreads();
                    buf = nb;
                }
            }
        }
        double comp[4];
        double cnt = 0.0;
        #pragma unroll
        for (int j = 0; j < 4; ++j) {
            double z2v = (double)bg2[c0 + j] + zA[j] + zB[j];
            double gw = 1.0 / (1.0 + exp(-z2v));
            double g = (double)Fs[c0 + j] * gw;
            double cm = (g > 0.3) ? 0.0 : g;
            comp[j] = cm;
            cnt += (fabs(cm) < 0.1) ? 1.0 : 0.0;
        }
        cnt = block_reduce_d(cnt, sm, tid, 0);
        const double cur_sp = cnt / 1024.0;

        double hid[16];
        #pragma unroll
        for (int h = 0; h < 16; ++h) {
            double hz = cur_sp * (double)wr1[h] + 0.1 * (double)wr1[16 + h] + (double)br1[h];
            hid[h] = (hz > 0.0) ? hz : 0.0;
        }
        double zr[4] = {(double)br2[c0], (double)br2[c0 + 1],
                        (double)br2[c0 + 2], (double)br2[c0 + 3]};
        #pragma unroll
        for (int h = 0; h < 16; ++h) {
            float4 w4 = *(const float4*)(wr2 + (size_t)h * 1024 + c0);
            zr[0] += hid[h] * (double)w4.x; zr[1] += hid[h] * (double)w4.y;
            zr[2] += hid[h] * (double)w4.z; zr[3] += hid[h] * (double)w4.w;
        }
        double dyn[4];
        #pragma unroll
        for (int j = 0; j < 4; ++j) {
            double rw = 1.0 / (1.0 + exp(-zr[j]));
            dyn[j] = comp[j] * rw;
        }

        double s = dyn[0] + dyn[1] + dyn[2] + dyn[3];
        s = block_reduce_d(s, sm, tid, 0);
        const double mean = s / 1024.0;

        double sq = 0.0;
        #pragma unroll
        for (int j = 0; j < 4; ++j) { double d = dyn[j] - mean; sq += d * d; }
        sq = block_reduce_d(sq, sm, tid, 0);
        const double sd = sqrt(sq / 1023.0);

        double mx = fmax(fmax(dyn[0], dyn[1]), fmax(dyn[2], dyn[3]));
        mx = block_reduce_d(mx, sm, tid, 1);

        double acc2 = (double)bm2[0];
        #pragma unroll
        for (int h = 0; h < 16; ++h) {
            double hz = mean * (double)wm1[h] + sd * (double)wm1[16 + h]
                      + mx * (double)wm1[32 + h] + (double)bm1[h];
            hz = (hz > 0.0) ? hz : 0.0;
            acc2 += hz * (double)wm2[h];
        }
        const double thr = 1.0 / (1.0 + exp(-acc2));

        float4 o4;
        o4.x = (float)((fabs(dyn[0]) > thr) ? dyn[0] : 0.0);
        o4.y = (float)((fabs(dyn[1]) > thr) ? dyn[1] : 0.0);
        o4.z = (float)((fabs(dyn[2]) > thr) ? dyn[2] : 0.0);
        o4.w = (float)((fabs(dyn[3]) > thr) ? dyn[3] : 0.0);
        *(float4*)(out + (size_t)row * 1024 + c0) = o4;
    }
}

// ---------------------------------------------------------------------------
// Workspace map (max offset 36 MiB + 256 KiB + 16 B — the bound validated in
// rounds 2-8; round 9's 38 MiB layout was never validated and may have been
// the container-crash cause):
//   [0,        32M)   h1 (fp32, 32768 x 256)
//   [32M,      34M)   elist1 (uint2 x 262144)
//   [34M,      35M)   wg2Th/wg2Tl (512K each)  -- dead after gemm2_mfma
//   [35M,      36M)   elist2 (uint2 x 131072)  -- first written by fix_near
//   [36M,      36M+128K)  rowlist
//   [36M+128K, 36M+256K)  corr
//   [36M+256K, +16B)      counters
// ---------------------------------------------------------------------------
extern "C" void kernel_launch(void* const* d_in, const int* in_sizes, int n_in,
                              void* d_out, int out_size, void* d_ws, size_t ws_size,
                              hipStream_t stream)
{
    const float* F   = (const float*)d_in[0];
    const float* wg1 = (const float*)d_in[1];
    const float* bg1 = (const float*)d_in[2];
    const float* wg2 = (const float*)d_in[3];
    const float* bg2 = (const float*)d_in[4];
    // d_in[5..8]: competition calculator — provably dead (win == False always)
    const float* wr1 = (const float*)d_in[9];
    const float* br1 = (const float*)d_in[10];
    const float* wr2 = (const float*)d_in[11];
    const float* br2 = (const float*)d_in[12];
    const float* wm1 = (const float*)d_in[13];
    const float* bm1 = (const float*)d_in[14];
    const float* wm2 = (const float*)d_in[15];
    const float* bm2 = (const float*)d_in[16];

    float* out = (float*)d_out;
    const int M = in_sizes[0] / 1024;                      // 32768

    char* ws = (char*)d_ws;
    float*          h1      = (float*)ws;                              // 32 MiB
    uint2*          elist1  = (uint2*)(ws + (32u << 20));              // 2 MiB
    unsigned short* wg2Th   = (unsigned short*)(ws + (34u << 20));     // 512 KiB
    unsigned short* wg2Tl   = (unsigned short*)(ws + (34u << 20) + (512u << 10));
    uint2*          elist2  = (uint2*)(ws + (35u << 20));              // 1 MiB
    unsigned*       rowlist = (unsigned*)(ws + (36u << 20));           // 128 KiB
    int*            corr    = (int*)(ws + (36u << 20) + (128u << 10)); // 128 KiB
    unsigned*       ctrs    = (unsigned*)(ws + (36u << 20) + (256u << 10));
    unsigned* ectr1 = ctrs, *ectr2 = ctrs + 1, *rctr = ctrs + 2;

    hipMemsetAsync(corr, 0, (size_t)M * sizeof(int) + 16, stream);
    split_wg2<<<1024, 256, 0, stream>>>(wg2, wg2Th, wg2Tl);
    gemm1_f32<<<dim3(M / TM, 256 / TN), 256, 0, stream>>>(F, wg1, bg1, h1, M);
    gemm2_mfma<<<dim3(M / 128, 1024 / 128), 256, 0, stream>>>(h1, wg2Th, wg2Tl, bg2, F,
                                                              out, ectr1, elist1, M);
    fix_near<<<2048, 256, 0, stream>>>(h1, F, wg2, bg2, ectr1, elist1, ectr2, elist2, out, corr);
    fix_full<<<1024, 256, 0, stream>>>(F, wg1, bg1, wg2, bg2, ectr2, elist2, out, corr);
    finalize_rows<<<M / 4, 256, 0, stream>>>(out, wr1, br1, wr2, br2, wm1, bm1, wm2, bm2,
                                             corr, rctr, rowlist);
    row_exact<<<2048, 256, 0, stream>>>(F, wg1, bg1, wg2, bg2, wr1, br1, wr2, br2,
                                        wm1, bm1, wm2, bm2, rctr, rowlist, out);
}